// Round 1
// baseline (2676.193 us; speedup 1.0000x reference)
//
#include <hip/hip_runtime.h>
#include <math.h>

#define NPTS 32768
#define KNN 16
#define DIM 128
// 1/sqrt(1 + 1e-5)
#define BN_RSQ 0.9999950000374997f

__device__ __forceinline__ float gelu_f(float v) {
    return 0.5f * v * (1.0f + erff(v * 0.70710678118654752440f));
}

// ---------------------------------------------------------------------------
// Precompute folded matrices per depth:
//   Weff[i]  = w1 @ w2 @ w3a[:64,:]          (3 x 128)
//   cbias[i] = (b1 @ w2 + b2) @ w3a[:64,:] + b3a   (128)
// ---------------------------------------------------------------------------
__global__ __launch_bounds__(128) void precompute_kernel(
    const float* __restrict__ nca_w1, const float* __restrict__ nca_b1,
    const float* __restrict__ nca_w2, const float* __restrict__ nca_b2,
    const float* __restrict__ nca_w3a, const float* __restrict__ nca_b3a,
    float* __restrict__ Weff, float* __restrict__ cbias)
{
    int i = blockIdx.x;
    int t = threadIdx.x;
    const float* w1 = nca_w1 + i * 3 * 64;
    const float* b1 = nca_b1 + i * 64;
    const float* w2 = nca_w2 + i * 64 * 64;
    const float* b2 = nca_b2 + i * 64;
    const float* w3a = nca_w3a + i * 128 * 128;
    const float* b3a = nca_b3a + i * 128;

    __shared__ float u[3][64];
    __shared__ float v[64];
    if (t < 64) {
        for (int r = 0; r < 3; ++r) {
            float s = 0.f;
            for (int m = 0; m < 64; ++m) s += w1[r * 64 + m] * w2[m * 64 + t];
            u[r][t] = s;
        }
        float s = 0.f;
        for (int m = 0; m < 64; ++m) s += b1[m] * w2[m * 64 + t];
        v[t] = s + b2[t];
    }
    __syncthreads();
    // t in [0,128)
    for (int r = 0; r < 3; ++r) {
        float s = 0.f;
        for (int m = 0; m < 64; ++m) s += u[r][m] * w3a[m * 128 + t];
        Weff[i * 384 + r * 128 + t] = s;
    }
    {
        float s = 0.f;
        for (int m = 0; m < 64; ++m) s += v[m] * w3a[m * 128 + t];
        cbias[i * 128 + t] = s + b3a[t];
    }
}

// ---------------------------------------------------------------------------
// Neighbor embedding: per point, for each of K neighbors run 10->16->32->128
// (BN+GELU between), max-pool over K, final BN, plus g_pos @ gpe_w add.
// Also writes dxyz [N,K,3] to workspace.
// ---------------------------------------------------------------------------
__global__ __launch_bounds__(128) void nbr_embed_kernel(
    const float* __restrict__ x, const float* __restrict__ xyz,
    const float* __restrict__ g_pos, const int* __restrict__ knn,
    const float* __restrict__ ne_w1, const float* __restrict__ ne_g1, const float* __restrict__ ne_b1,
    const float* __restrict__ ne_w2, const float* __restrict__ ne_g2, const float* __restrict__ ne_b2,
    const float* __restrict__ ne_w3, const float* __restrict__ nbr_g, const float* __restrict__ nbr_b,
    const float* __restrict__ gpe_w,
    float* __restrict__ dxyz_out, float* __restrict__ feat)
{
    int n = blockIdx.x;
    int t = threadIdx.x;
    __shared__ int idx[16];
    __shared__ float nb[10];
    __shared__ float h1[16];
    __shared__ float h2[32];
    __shared__ float gp[64];
    __shared__ float xyzn[3];

    if (t < 16) idx[t] = knn[n * 16 + t];
    if (t < 3)  xyzn[t] = xyz[n * 3 + t];
    if (t < 64) gp[t] = g_pos[n * 64 + t];
    __syncthreads();

    float mx = -1e30f;
    for (int k = 0; k < 16; ++k) {
        int id = idx[k];
        if (t < 3) {
            float d = xyz[id * 3 + t] - xyzn[t];
            nb[t] = d;
            dxyz_out[(size_t)n * 48 + k * 3 + t] = d;
        } else if (t < 10) {
            nb[t] = x[id * 7 + (t - 3)];
        }
        __syncthreads();
        if (t < 16) {
            float s = 0.f;
            #pragma unroll
            for (int j = 0; j < 10; ++j) s += nb[j] * ne_w1[j * 16 + t];
            s = s * (ne_g1[t] * BN_RSQ) + ne_b1[t];
            h1[t] = gelu_f(s);
        }
        __syncthreads();
        if (t < 32) {
            float s = 0.f;
            #pragma unroll
            for (int j = 0; j < 16; ++j) s += h1[j] * ne_w2[j * 32 + t];
            s = s * (ne_g2[t] * BN_RSQ) + ne_b2[t];
            h2[t] = gelu_f(s);
        }
        __syncthreads();
        {
            float s = 0.f;
            #pragma unroll
            for (int j = 0; j < 32; ++j) s += h2[j] * ne_w3[j * 128 + t];
            mx = fmaxf(mx, s);
        }
        __syncthreads();
    }
    float fv = mx * (nbr_g[t] * BN_RSQ) + nbr_b[t];
    float ga = 0.f;
    #pragma unroll 8
    for (int j = 0; j < 64; ++j) ga += gp[j] * gpe_w[j * 128 + t];
    feat[(size_t)n * 128 + t] = fv + ga;
}

// ---------------------------------------------------------------------------
// Residual MLP: feat += BN(GELU(feat @ w1 + b1) @ w2, g, b)
// 4 points per block, 256 threads.
// ---------------------------------------------------------------------------
__global__ __launch_bounds__(256) void mlp_res_kernel(
    float* __restrict__ feat,
    const float* __restrict__ w1, const float* __restrict__ b1,
    const float* __restrict__ w2, const float* __restrict__ g, const float* __restrict__ b)
{
    int n0 = blockIdx.x * 4;
    int t = threadIdx.x;
    __shared__ __align__(16) float fin[4][128];
    __shared__ __align__(16) float h[4][256];

    for (int v = t; v < 512; v += 256) fin[v >> 7][v & 127] = feat[(size_t)n0 * 128 + v];
    __syncthreads();

    float acc[4];
    #pragma unroll
    for (int p = 0; p < 4; ++p) acc[p] = b1[t];
    for (int j = 0; j < 128; j += 4) {
        float wa = w1[(j + 0) * 256 + t];
        float wb = w1[(j + 1) * 256 + t];
        float wc = w1[(j + 2) * 256 + t];
        float wd = w1[(j + 3) * 256 + t];
        #pragma unroll
        for (int p = 0; p < 4; ++p) {
            float4 f = *(const float4*)&fin[p][j];
            acc[p] += f.x * wa + f.y * wb + f.z * wc + f.w * wd;
        }
    }
    #pragma unroll
    for (int p = 0; p < 4; ++p) h[p][t] = gelu_f(acc[p]);
    __syncthreads();

    int c = t & 127, pb = t >> 7;   // pb in {0,1}, handles points pb and pb+2
    float a0 = 0.f, a1 = 0.f;
    for (int j = 0; j < 256; j += 4) {
        float wa = w2[(j + 0) * 128 + c];
        float wb = w2[(j + 1) * 128 + c];
        float wc = w2[(j + 2) * 128 + c];
        float wd = w2[(j + 3) * 128 + c];
        float4 ha = *(const float4*)&h[pb][j];
        float4 hb = *(const float4*)&h[pb + 2][j];
        a0 += ha.x * wa + ha.y * wb + ha.z * wc + ha.w * wd;
        a1 += hb.x * wa + hb.y * wb + hb.z * wc + hb.w * wd;
    }
    float gs = g[c] * BN_RSQ, bb = b[c];
    feat[(size_t)(n0 + pb) * 128 + c]     = fin[pb][c]     + a0 * gs + bb;
    feat[(size_t)(n0 + pb + 2) * 128 + c] = fin[pb + 2][c] + a1 * gs + bb;
}

// ---------------------------------------------------------------------------
// Plain 128->128 linear, no bias: out = in @ W.  4 points/block, 128 threads.
// ---------------------------------------------------------------------------
__global__ __launch_bounds__(128) void linear128_kernel(
    float* __restrict__ out, const float* __restrict__ in, const float* __restrict__ W)
{
    int n0 = blockIdx.x * 4;
    int t = threadIdx.x;
    __shared__ __align__(16) float fin[4][128];
    for (int v = t; v < 512; v += 128) fin[v >> 7][v & 127] = in[(size_t)n0 * 128 + v];
    __syncthreads();
    float acc[4] = {0.f, 0.f, 0.f, 0.f};
    for (int j = 0; j < 128; j += 4) {
        float wa = W[(j + 0) * 128 + t];
        float wb = W[(j + 1) * 128 + t];
        float wc = W[(j + 2) * 128 + t];
        float wd = W[(j + 3) * 128 + t];
        #pragma unroll
        for (int p = 0; p < 4; ++p) {
            float4 f = *(const float4*)&fin[p][j];
            acc[p] += f.x * wa + f.y * wb + f.z * wc + f.w * wd;
        }
    }
    #pragma unroll
    for (int p = 0; p < 4; ++p) out[(size_t)(n0 + p) * 128 + t] = acc[p];
}

// ---------------------------------------------------------------------------
// LFA: the heavy kernel. Per point n:
//   p0[k] = dxyz@w1+b1 (64); p_local = max_k p0
//   tv[c] = p_local @ w3a_bot + cbias   (precomputed fold)
//   a[k][c] = dxyz[k] @ Weff + tv[c];  gLDS = GELU(a)
//   pe[k][c] = gLDS[k] @ w3b[:,c] + b3b[c]
//   y[c] = max_k( xp[knn[k]][c] + pe[k][c] ) - xp[n][c]
//   feat[n] += BN(y, lg, lb)
// ---------------------------------------------------------------------------
__global__ __launch_bounds__(128) void lfa_kernel(
    float* __restrict__ feat, const float* __restrict__ xp,
    const float* __restrict__ dxyz, const int* __restrict__ knn,
    const float* __restrict__ w1, const float* __restrict__ b1,
    const float* __restrict__ w3a, const float* __restrict__ Weff,
    const float* __restrict__ cbias, const float* __restrict__ w3b,
    const float* __restrict__ b3b,
    const float* __restrict__ lg, const float* __restrict__ lb)
{
    int n = blockIdx.x;
    int t = threadIdx.x;
    __shared__ int idx[16];
    __shared__ __align__(16) float dx[16][3];
    __shared__ float pl[64];
    __shared__ __align__(16) float gld[16][128];
    __shared__ float xpself[128];
    __shared__ __align__(16) float red[4][128];

    if (t < 16) idx[t] = knn[n * 16 + t];
    if (t < 48) ((float*)dx)[t] = dxyz[(size_t)n * 48 + t];
    xpself[t] = xp[(size_t)n * 128 + t];
    __syncthreads();

    // p_local
    if (t < 64) {
        float m = -1e30f;
        #pragma unroll 4
        for (int k = 0; k < 16; ++k) {
            float s = b1[t] + dx[k][0] * w1[t] + dx[k][1] * w1[64 + t] + dx[k][2] * w1[128 + t];
            m = fmaxf(m, s);
        }
        pl[t] = m;
    }
    __syncthreads();

    // tv (register) + phase 1: gld[k][t] = GELU(a)
    {
        const float* B = w3a + 64 * 128;
        float tv = cbias[t];
        #pragma unroll 8
        for (int m = 0; m < 64; ++m) tv += pl[m] * B[m * 128 + t];
        float we0 = Weff[t], we1 = Weff[128 + t], we2 = Weff[256 + t];
        #pragma unroll
        for (int k = 0; k < 16; ++k) {
            float s = tv + dx[k][0] * we0 + dx[k][1] * we1 + dx[k][2] * we2;
            gld[k][t] = gelu_f(s);
        }
    }
    __syncthreads();

    // phase 2: register-tiled 16x128 @ 128x128 + gather + max
    int cg = t & 31;         // column group: columns cg*4 .. cg*4+3
    int kg = t >> 5;         // k group: rows kg*4 .. kg*4+3
    float acc[4][4];
    #pragma unroll
    for (int a = 0; a < 4; ++a)
        #pragma unroll
        for (int bq = 0; bq < 4; ++bq) acc[a][bq] = 0.f;

    const int cbase = cg * 4;
    for (int j = 0; j < 128; j += 4) {
        float4 w0 = *(const float4*)&w3b[(j + 0) * 128 + cbase];
        float4 w1v = *(const float4*)&w3b[(j + 1) * 128 + cbase];
        float4 w2v = *(const float4*)&w3b[(j + 2) * 128 + cbase];
        float4 w3v = *(const float4*)&w3b[(j + 3) * 128 + cbase];
        #pragma unroll
        for (int kk = 0; kk < 4; ++kk) {
            float4 gk = *(const float4*)&gld[kg * 4 + kk][j];
            acc[kk][0] += gk.x * w0.x + gk.y * w1v.x + gk.z * w2v.x + gk.w * w3v.x;
            acc[kk][1] += gk.x * w0.y + gk.y * w1v.y + gk.z * w2v.y + gk.w * w3v.y;
            acc[kk][2] += gk.x * w0.z + gk.y * w1v.z + gk.z * w2v.z + gk.w * w3v.z;
            acc[kk][3] += gk.x * w0.w + gk.y * w1v.w + gk.z * w2v.w + gk.w * w3v.w;
        }
    }

    float4 bb = *(const float4*)&b3b[cbase];
    float m0 = -1e30f, m1 = -1e30f, m2 = -1e30f, m3 = -1e30f;
    #pragma unroll
    for (int kk = 0; kk < 4; ++kk) {
        int id = idx[kg * 4 + kk];
        float4 xq = *(const float4*)&xp[(size_t)id * 128 + cbase];
        m0 = fmaxf(m0, acc[kk][0] + bb.x + xq.x);
        m1 = fmaxf(m1, acc[kk][1] + bb.y + xq.y);
        m2 = fmaxf(m2, acc[kk][2] + bb.z + xq.z);
        m3 = fmaxf(m3, acc[kk][3] + bb.w + xq.w);
    }
    red[kg][cbase + 0] = m0;
    red[kg][cbase + 1] = m1;
    red[kg][cbase + 2] = m2;
    red[kg][cbase + 3] = m3;
    __syncthreads();

    float mm = fmaxf(fmaxf(red[0][t], red[1][t]), fmaxf(red[2][t], red[3][t]));
    float y = mm - xpself[t];
    feat[(size_t)n * 128 + t] += y * (lg[t] * BN_RSQ) + lb[t];
}

// ---------------------------------------------------------------------------
// Postproj: out = BN(feat, g, b) @ pp_w   (128 -> 256). 4 points/block.
// ---------------------------------------------------------------------------
__global__ __launch_bounds__(256) void postproj_kernel(
    float* __restrict__ out, const float* __restrict__ feat,
    const float* __restrict__ g, const float* __restrict__ b, const float* __restrict__ W)
{
    int n0 = blockIdx.x * 4;
    int t = threadIdx.x;
    __shared__ __align__(16) float fin[4][128];
    for (int v = t; v < 512; v += 256) {
        int c = v & 127;
        fin[v >> 7][c] = feat[(size_t)n0 * 128 + v] * (g[c] * BN_RSQ) + b[c];
    }
    __syncthreads();
    float acc[4] = {0.f, 0.f, 0.f, 0.f};
    for (int j = 0; j < 128; j += 4) {
        float wa = W[(j + 0) * 256 + t];
        float wb = W[(j + 1) * 256 + t];
        float wc = W[(j + 2) * 256 + t];
        float wd = W[(j + 3) * 256 + t];
        #pragma unroll
        for (int p = 0; p < 4; ++p) {
            float4 f = *(const float4*)&fin[p][j];
            acc[p] += f.x * wa + f.y * wb + f.z * wc + f.w * wd;
        }
    }
    #pragma unroll
    for (int p = 0; p < 4; ++p) out[(size_t)(n0 + p) * 256 + t] = acc[p];
}

// ---------------------------------------------------------------------------
extern "C" void kernel_launch(void* const* d_in, const int* in_sizes, int n_in,
                              void* d_out, int out_size, void* d_ws, size_t ws_size,
                              hipStream_t stream) {
    const float* x       = (const float*)d_in[0];
    const float* xyz     = (const float*)d_in[1];
    const float* g_pos   = (const float*)d_in[2];
    const float* ne_w1   = (const float*)d_in[3];
    const float* ne_g1   = (const float*)d_in[4];
    const float* ne_b1   = (const float*)d_in[5];
    const float* ne_w2   = (const float*)d_in[6];
    const float* ne_g2   = (const float*)d_in[7];
    const float* ne_b2   = (const float*)d_in[8];
    const float* ne_w3   = (const float*)d_in[9];
    const float* nbr_g   = (const float*)d_in[10];
    const float* nbr_b   = (const float*)d_in[11];
    const float* gpe_w   = (const float*)d_in[12];
    const float* bm_w1   = (const float*)d_in[13];
    const float* bm_b1   = (const float*)d_in[14];
    const float* bm_w2   = (const float*)d_in[15];
    const float* bm_g    = (const float*)d_in[16];
    const float* bm_b    = (const float*)d_in[17];
    const float* lfa_proj = (const float*)d_in[18];
    const float* lfa_g   = (const float*)d_in[19];
    const float* lfa_b   = (const float*)d_in[20];
    const float* nca_w1  = (const float*)d_in[21];
    const float* nca_b1  = (const float*)d_in[22];
    const float* nca_w2  = (const float*)d_in[23];
    const float* nca_b2  = (const float*)d_in[24];
    const float* nca_w3a = (const float*)d_in[25];
    const float* nca_b3a = (const float*)d_in[26];
    const float* nca_w3b = (const float*)d_in[27];
    const float* nca_b3b = (const float*)d_in[28];
    const float* m_w1    = (const float*)d_in[29];
    const float* m_b1    = (const float*)d_in[30];
    const float* m_w2    = (const float*)d_in[31];
    const float* m_g     = (const float*)d_in[32];
    const float* m_b     = (const float*)d_in[33];
    const float* pp_g    = (const float*)d_in[34];
    const float* pp_b    = (const float*)d_in[35];
    const float* pp_w    = (const float*)d_in[36];
    const int*   knn     = (const int*)d_in[37];

    float* ws    = (float*)d_ws;
    float* dxyz  = ws;                                  // N*48
    float* feat  = dxyz + (size_t)NPTS * 48;            // N*128
    float* xp    = feat + (size_t)NPTS * 128;           // N*128
    float* Weff  = xp + (size_t)NPTS * 128;             // 4*384
    float* cbias = Weff + 4 * 384;                      // 4*128
    float* out   = (float*)d_out;

    hipLaunchKernelGGL(precompute_kernel, dim3(4), dim3(128), 0, stream,
                       nca_w1, nca_b1, nca_w2, nca_b2, nca_w3a, nca_b3a, Weff, cbias);
    hipLaunchKernelGGL(nbr_embed_kernel, dim3(NPTS), dim3(128), 0, stream,
                       x, xyz, g_pos, knn,
                       ne_w1, ne_g1, ne_b1, ne_w2, ne_g2, ne_b2, ne_w3,
                       nbr_g, nbr_b, gpe_w, dxyz, feat);
    hipLaunchKernelGGL(mlp_res_kernel, dim3(NPTS / 4), dim3(256), 0, stream,
                       feat, bm_w1, bm_b1, bm_w2, bm_g, bm_b);
    for (int i = 0; i < 4; ++i) {
        hipLaunchKernelGGL(linear128_kernel, dim3(NPTS / 4), dim3(128), 0, stream,
                           xp, feat, lfa_proj + (size_t)i * 128 * 128);
        hipLaunchKernelGGL(lfa_kernel, dim3(NPTS), dim3(128), 0, stream,
                           feat, xp, dxyz, knn,
                           nca_w1 + (size_t)i * 192, nca_b1 + (size_t)i * 64,
                           nca_w3a + (size_t)i * 16384,
                           Weff + (size_t)i * 384, cbias + (size_t)i * 128,
                           nca_w3b + (size_t)i * 16384, nca_b3b + (size_t)i * 128,
                           lfa_g + (size_t)i * 128, lfa_b + (size_t)i * 128);
        if (i & 1) {
            int j = i >> 1;
            hipLaunchKernelGGL(mlp_res_kernel, dim3(NPTS / 4), dim3(256), 0, stream,
                               feat, m_w1 + (size_t)j * 128 * 256, m_b1 + (size_t)j * 256,
                               m_w2 + (size_t)j * 256 * 128, m_g + (size_t)j * 128,
                               m_b + (size_t)j * 128);
        }
    }
    hipLaunchKernelGGL(postproj_kernel, dim3(NPTS / 4), dim3(256), 0, stream,
                       out, feat, pp_g, pp_b, pp_w);
}

// Round 2
// 1471.873 us; speedup vs baseline: 1.8182x; 1.8182x over previous
//
#include <hip/hip_runtime.h>
#include <math.h>

#define NPTS 32768
#define BN_RSQ 0.9999950000374997f
#define LFA_P 8
#define NBR_P 8

typedef __attribute__((ext_vector_type(8))) short short8;
typedef __attribute__((ext_vector_type(4))) short short4v;
typedef __attribute__((ext_vector_type(4))) float floatx4;

__device__ __forceinline__ float gelu_f(float v) {
    return 0.5f * v * (1.0f + erff(v * 0.70710678118654752440f));
}
__device__ __forceinline__ unsigned short f2bf(float f) {
    unsigned u = __float_as_uint(f);
    u += 0x7fffu + ((u >> 16) & 1u);
    return (unsigned short)(u >> 16);
}

// ---------------------------------------------------------------------------
// Folded matrices per depth: Weff[i] = w1@w2@w3a_top (3x128),
// cbias[i] = (b1@w2 + b2)@w3a_top + b3a (128)
// ---------------------------------------------------------------------------
__global__ __launch_bounds__(128) void precompute_kernel(
    const float* __restrict__ nca_w1, const float* __restrict__ nca_b1,
    const float* __restrict__ nca_w2, const float* __restrict__ nca_b2,
    const float* __restrict__ nca_w3a, const float* __restrict__ nca_b3a,
    float* __restrict__ Weff, float* __restrict__ cbias)
{
    int i = blockIdx.x;
    int t = threadIdx.x;
    const float* w1 = nca_w1 + i * 3 * 64;
    const float* b1 = nca_b1 + i * 64;
    const float* w2 = nca_w2 + i * 64 * 64;
    const float* b2 = nca_b2 + i * 64;
    const float* w3a = nca_w3a + i * 128 * 128;
    const float* b3a = nca_b3a + i * 128;

    __shared__ float u[3][64];
    __shared__ float v[64];
    if (t < 64) {
        for (int r = 0; r < 3; ++r) {
            float s = 0.f;
            for (int m = 0; m < 64; ++m) s += w1[r * 64 + m] * w2[m * 64 + t];
            u[r][t] = s;
        }
        float s = 0.f;
        for (int m = 0; m < 64; ++m) s += b1[m] * w2[m * 64 + t];
        v[t] = s + b2[t];
    }
    __syncthreads();
    for (int r = 0; r < 3; ++r) {
        float s = 0.f;
        for (int m = 0; m < 64; ++m) s += u[r][m] * w3a[m * 128 + t];
        Weff[i * 384 + r * 128 + t] = s;
    }
    {
        float s = 0.f;
        for (int m = 0; m < 64; ++m) s += v[m] * w3a[m * 128 + t];
        cbias[i * 128 + t] = s + b3a[t];
    }
}

// ---------------------------------------------------------------------------
// Pack w3b (4 depths) and ne_w3 into MFMA B-fragment order, bf16.
// B-frag for 16x16x32: lane holds B[k = chunk*32 + (lane>>4)*8 + j][n = tile*16 + (lane&15)]
// ---------------------------------------------------------------------------
__global__ __launch_bounds__(64) void pack_kernel(
    const float* __restrict__ nca_w3b, const float* __restrict__ ne_w3,
    unsigned short* __restrict__ w3bPack, unsigned short* __restrict__ nePack)
{
    int b = blockIdx.x, l = threadIdx.x;
    if (b < 128) {
        int d = b >> 5, tt = (b >> 2) & 7, ch = b & 3;
        const float* W = nca_w3b + (size_t)d * 16384;
        unsigned short* o = w3bPack + ((size_t)b * 64 + l) * 8;
        #pragma unroll
        for (int j = 0; j < 8; ++j) {
            int kk = ch * 32 + (l >> 4) * 8 + j;
            int nn = tt * 16 + (l & 15);
            o[j] = f2bf(W[kk * 128 + nn]);
        }
    } else {
        int tt = b - 128;
        unsigned short* o = nePack + ((size_t)tt * 64 + l) * 8;
        #pragma unroll
        for (int j = 0; j < 8; ++j) {
            int kk = (l >> 4) * 8 + j;
            int nn = tt * 16 + (l & 15);
            o[j] = f2bf(ne_w3[kk * 128 + nn]);
        }
    }
}

// ---------------------------------------------------------------------------
// Neighbor embedding, MFMA version. Block = 128 threads = 2 waves, 1 point
// per iteration. Layers 1-2: 8 lanes per neighbor (intra-wave, no barriers).
// Layer 3 (32->128) + max-pool over K via MFMA (wave h does N-tiles h*4..h*4+3).
// ---------------------------------------------------------------------------
__global__ __launch_bounds__(128) void nbr_embed_mfma(
    const float* __restrict__ x, const float* __restrict__ xyz,
    const float* __restrict__ g_pos, const int* __restrict__ knn,
    const float* __restrict__ ne_w1, const float* __restrict__ ne_g1, const float* __restrict__ ne_b1,
    const float* __restrict__ ne_w2, const float* __restrict__ ne_g2, const float* __restrict__ ne_b2,
    const unsigned short* __restrict__ nePack,
    const float* __restrict__ nbr_g, const float* __restrict__ nbr_b,
    const float* __restrict__ gpe_w,
    float* __restrict__ dxyz_out, float* __restrict__ feat)
{
    int t = threadIdx.x;
    int h = t >> 6, l = t & 63;
    int k = t >> 3, r = t & 7;
    int q = l >> 4, r16 = l & 15;
    int cown = h * 64 + l;

    __shared__ __align__(16) float nbS[16][12];
    __shared__ float h1S[16][17];
    __shared__ __align__(16) unsigned short h2S[16][40];
    __shared__ __align__(16) float gpS[64];
    __shared__ int idS[16];

    short8 bf[4];
    #pragma unroll
    for (int tt = 0; tt < 4; ++tt)
        bf[tt] = ((const short8*)nePack)[(h * 4 + tt) * 64 + l];

    float w1a[10], w1b[10];
    #pragma unroll
    for (int j = 0; j < 10; ++j) { w1a[j] = ne_w1[j * 16 + r]; w1b[j] = ne_w1[j * 16 + r + 8]; }
    float g1a = ne_g1[r] * BN_RSQ,     b1a = ne_b1[r];
    float g1b = ne_g1[r + 8] * BN_RSQ, b1b = ne_b1[r + 8];
    float4 w2c[16];
    #pragma unroll
    for (int j = 0; j < 16; ++j) w2c[j] = *(const float4*)&ne_w2[j * 32 + r * 4];
    float4 g2v = *(const float4*)&ne_g2[r * 4];
    g2v.x *= BN_RSQ; g2v.y *= BN_RSQ; g2v.z *= BN_RSQ; g2v.w *= BN_RSQ;
    float4 b2v = *(const float4*)&ne_b2[r * 4];
    float bng = nbr_g[cown] * BN_RSQ, bnb = nbr_b[cown];

    for (int it = 0; it < NBR_P; ++it) {
        int n = blockIdx.x * NBR_P + it;
        if (t < 16) idS[t] = knn[n * 16 + t];
        if (t < 64) gpS[t] = g_pos[(size_t)n * 64 + t];
        __syncthreads();

        int id = idS[k];
        if (r < 3) {
            float d = xyz[(size_t)id * 3 + r] - xyz[(size_t)n * 3 + r];
            nbS[k][r] = d;
            dxyz_out[(size_t)n * 48 + k * 3 + r] = d;
        } else {
            nbS[k][r] = x[(size_t)id * 7 + (r - 3)];
        }
        if (r < 2) nbS[k][8 + r] = x[(size_t)id * 7 + 5 + r];

        // h1: outputs r and r+8 for neighbor k (intra-wave dep, no barrier)
        float s0 = 0.f, s1 = 0.f;
        #pragma unroll
        for (int j = 0; j < 10; ++j) {
            float nv = nbS[k][j];
            s0 += nv * w1a[j];
            s1 += nv * w1b[j];
        }
        h1S[k][r]     = gelu_f(s0 * g1a + b1a);
        h1S[k][r + 8] = gelu_f(s1 * g1b + b1b);

        // h2: outputs 4r..4r+3 for neighbor k
        float a0 = 0.f, a1 = 0.f, a2 = 0.f, a3 = 0.f;
        #pragma unroll
        for (int j = 0; j < 16; ++j) {
            float hv = h1S[k][j];
            a0 += hv * w2c[j].x; a1 += hv * w2c[j].y;
            a2 += hv * w2c[j].z; a3 += hv * w2c[j].w;
        }
        a0 = gelu_f(a0 * g2v.x + b2v.x);
        a1 = gelu_f(a1 * g2v.y + b2v.y);
        a2 = gelu_f(a2 * g2v.z + b2v.z);
        a3 = gelu_f(a3 * g2v.w + b2v.w);
        {
            unsigned lo = (unsigned)f2bf(a0) | ((unsigned)f2bf(a1) << 16);
            unsigned hi = (unsigned)f2bf(a2) | ((unsigned)f2bf(a3) << 16);
            unsigned* h2p = (unsigned*)&h2S[k][r * 4];
            h2p[0] = lo; h2p[1] = hi;
        }
        __syncthreads();

        // MFMA: A = h2 [16 nbrs x 32], B = ne_w3 tiles
        short4v alo = *(const short4v*)&h2S[r16][q * 8];
        short4v ahi = *(const short4v*)&h2S[r16][q * 8 + 4];
        short8 af = __builtin_shufflevector(alo, ahi, 0, 1, 2, 3, 4, 5, 6, 7);
        floatx4 z4 = {0.f, 0.f, 0.f, 0.f};
        floatx4 acc[4];
        #pragma unroll
        for (int tt = 0; tt < 4; ++tt)
            acc[tt] = __builtin_amdgcn_mfma_f32_16x16x32_bf16(af, bf[tt], z4, 0, 0, 0);

        // gpe for owned column
        float gp = 0.f;
        #pragma unroll 4
        for (int j = 0; j < 64; j += 4) {
            float4 g4 = *(const float4*)&gpS[j];
            gp += g4.x * gpe_w[(j + 0) * 128 + cown];
            gp += g4.y * gpe_w[(j + 1) * 128 + cown];
            gp += g4.z * gpe_w[(j + 2) * 128 + cown];
            gp += g4.w * gpe_w[(j + 3) * 128 + cown];
        }

        // max over 16 neighbors (C/D: col=lane&15, row=quad*4+reg)
        float keep = 0.f;
        #pragma unroll
        for (int tt = 0; tt < 4; ++tt) {
            float mx = fmaxf(fmaxf(acc[tt].x, acc[tt].y), fmaxf(acc[tt].z, acc[tt].w));
            mx = fmaxf(mx, __shfl_xor(mx, 16));
            mx = fmaxf(mx, __shfl_xor(mx, 32));
            if (tt == q) keep = mx;
        }
        feat[(size_t)n * 128 + cown] = keep * bng + bnb + gp;
        __syncthreads();
    }
}

// ---------------------------------------------------------------------------
// Residual MLP: feat += BN(GELU(feat @ w1 + b1) @ w2, g, b). Unchanged (R1).
// ---------------------------------------------------------------------------
__global__ __launch_bounds__(256) void mlp_res_kernel(
    float* __restrict__ feat,
    const float* __restrict__ w1, const float* __restrict__ b1,
    const float* __restrict__ w2, const float* __restrict__ g, const float* __restrict__ b)
{
    int n0 = blockIdx.x * 4;
    int t = threadIdx.x;
    __shared__ __align__(16) float fin[4][128];
    __shared__ __align__(16) float h[4][256];

    for (int v = t; v < 512; v += 256) fin[v >> 7][v & 127] = feat[(size_t)n0 * 128 + v];
    __syncthreads();

    float acc[4];
    #pragma unroll
    for (int p = 0; p < 4; ++p) acc[p] = b1[t];
    for (int j = 0; j < 128; j += 4) {
        float wa = w1[(j + 0) * 256 + t];
        float wb = w1[(j + 1) * 256 + t];
        float wc = w1[(j + 2) * 256 + t];
        float wd = w1[(j + 3) * 256 + t];
        #pragma unroll
        for (int p = 0; p < 4; ++p) {
            float4 f = *(const float4*)&fin[p][j];
            acc[p] += f.x * wa + f.y * wb + f.z * wc + f.w * wd;
        }
    }
    #pragma unroll
    for (int p = 0; p < 4; ++p) h[p][t] = gelu_f(acc[p]);
    __syncthreads();

    int c = t & 127, pb = t >> 7;
    float a0 = 0.f, a1 = 0.f;
    for (int j = 0; j < 256; j += 4) {
        float wa = w2[(j + 0) * 128 + c];
        float wb = w2[(j + 1) * 128 + c];
        float wc = w2[(j + 2) * 128 + c];
        float wd = w2[(j + 3) * 128 + c];
        float4 ha = *(const float4*)&h[pb][j];
        float4 hb = *(const float4*)&h[pb + 2][j];
        a0 += ha.x * wa + ha.y * wb + ha.z * wc + ha.w * wd;
        a1 += hb.x * wa + hb.y * wb + hb.z * wc + hb.w * wd;
    }
    float gs = g[c] * BN_RSQ, bb = b[c];
    feat[(size_t)(n0 + pb) * 128 + c]     = fin[pb][c]     + a0 * gs + bb;
    feat[(size_t)(n0 + pb + 2) * 128 + c] = fin[pb + 2][c] + a1 * gs + bb;
}

// ---------------------------------------------------------------------------
// Plain 128->128 linear, no bias. Unchanged (R1).
// ---------------------------------------------------------------------------
__global__ __launch_bounds__(128) void linear128_kernel(
    float* __restrict__ out, const float* __restrict__ in, const float* __restrict__ W)
{
    int n0 = blockIdx.x * 4;
    int t = threadIdx.x;
    __shared__ __align__(16) float fin[4][128];
    for (int v = t; v < 512; v += 128) fin[v >> 7][v & 127] = in[(size_t)n0 * 128 + v];
    __syncthreads();
    float acc[4] = {0.f, 0.f, 0.f, 0.f};
    for (int j = 0; j < 128; j += 4) {
        float wa = W[(j + 0) * 128 + t];
        float wb = W[(j + 1) * 128 + t];
        float wc = W[(j + 2) * 128 + t];
        float wd = W[(j + 3) * 128 + t];
        #pragma unroll
        for (int p = 0; p < 4; ++p) {
            float4 f = *(const float4*)&fin[p][j];
            acc[p] += f.x * wa + f.y * wb + f.z * wc + f.w * wd;
        }
    }
    #pragma unroll
    for (int p = 0; p < 4; ++p) out[(size_t)(n0 + p) * 128 + t] = acc[p];
}

// ---------------------------------------------------------------------------
// LFA, MFMA version. Block = 256 = 4 independent waves, 1 point per wave per
// iteration, zero barriers. w3b held entirely in registers (B-frag order).
// Per point: p_local -> tv fold -> GELU(a) to LDS bf16 -> 32 MFMAs ->
// fused gather+max+BN epilogue.
// ---------------------------------------------------------------------------
__global__ __launch_bounds__(256, 2) void lfa_mfma_kernel(
    float* __restrict__ feat, const float* __restrict__ xp,
    const float* __restrict__ dxyz, const int* __restrict__ knn,
    const float* __restrict__ w1, const float* __restrict__ b1,
    const float* __restrict__ w3aB, const float* __restrict__ Weff,
    const float* __restrict__ cbias, const unsigned short* __restrict__ w3bPack,
    const float* __restrict__ b3b, const float* __restrict__ lg, const float* __restrict__ lb)
{
    int w = threadIdx.x >> 6;
    int l = threadIdx.x & 63;
    int q = l >> 4, r16 = l & 15;

    __shared__ __align__(16) unsigned short gS[4][16][136];
    __shared__ __align__(16) float plS[4][64];
    __shared__ __align__(16) float dxS[4][64];
    __shared__ int idS[4][16];

    short8 bfr[8][4];
    {
        const short8* bp = (const short8*)w3bPack;
        #pragma unroll
        for (int tt = 0; tt < 8; ++tt)
            #pragma unroll
            for (int ch = 0; ch < 4; ++ch)
                bfr[tt][ch] = bp[(tt * 4 + ch) * 64 + l];
    }
    int c0 = 2 * l;
    float2 we0 = *(const float2*)&Weff[c0];
    float2 we1 = *(const float2*)&Weff[128 + c0];
    float2 we2 = *(const float2*)&Weff[256 + c0];
    float2 tvb = *(const float2*)&cbias[c0];
    float w1r0 = w1[l], w1r1 = w1[64 + l], w1r2 = w1[128 + l], b1l = b1[l];
    float b3b0 = b3b[l], b3b1 = b3b[l + 64];
    float lg0 = lg[l] * BN_RSQ, lg1 = lg[l + 64] * BN_RSQ;
    float lb0 = lb[l], lb1 = lb[l + 64];

    for (int it = 0; it < LFA_P; ++it) {
        int n = (blockIdx.x * LFA_P + it) * 4 + w;
        if (l < 16) idS[w][l] = knn[n * 16 + l];
        if (l < 48) {
            float v = dxyz[(size_t)n * 48 + l];
            int kk = l / 3, rr = l - kk * 3;
            dxS[w][kk * 4 + rr] = v;
        }

        // p_local (lane l owns hidden dim l)
        float plv = -1e30f;
        #pragma unroll
        for (int k = 0; k < 16; ++k) {
            float4 d4 = *(const float4*)&dxS[w][k * 4];
            plv = fmaxf(plv, b1l + d4.x * w1r0 + d4.y * w1r1 + d4.z * w1r2);
        }
        plS[w][l] = plv;

        // tv = cbias + p_local @ w3a_bot  (cols 2l, 2l+1)
        float tv0 = tvb.x, tv1 = tvb.y;
        {
            const float2* Bp = (const float2*)w3aB;
            #pragma unroll 4
            for (int m = 0; m < 64; m += 4) {
                float4 p4 = *(const float4*)&plS[w][m];
                float2 bv0 = Bp[(m + 0) * 64 + l];
                float2 bv1 = Bp[(m + 1) * 64 + l];
                float2 bv2 = Bp[(m + 2) * 64 + l];
                float2 bv3 = Bp[(m + 3) * 64 + l];
                tv0 += p4.x * bv0.x + p4.y * bv1.x + p4.z * bv2.x + p4.w * bv3.x;
                tv1 += p4.x * bv0.y + p4.y * bv1.y + p4.z * bv2.y + p4.w * bv3.y;
            }
        }

        // g = GELU(tv + dxyz @ Weff), bf16 pairs to LDS
        #pragma unroll
        for (int k = 0; k < 16; ++k) {
            float4 d4 = *(const float4*)&dxS[w][k * 4];
            float s0 = tv0 + d4.x * we0.x + d4.y * we1.x + d4.z * we2.x;
            float s1 = tv1 + d4.x * we0.y + d4.y * we1.y + d4.z * we2.y;
            unsigned gw = (unsigned)f2bf(gelu_f(s0)) | ((unsigned)f2bf(gelu_f(s1)) << 16);
            ((unsigned*)&gS[w][k][0])[l] = gw;
        }

        // 16x128 @ 128x128 via 32 MFMAs
        floatx4 z4 = {0.f, 0.f, 0.f, 0.f};
        floatx4 acc[8];
        #pragma unroll
        for (int tt = 0; tt < 8; ++tt) acc[tt] = z4;
        #pragma unroll
        for (int ch = 0; ch < 4; ++ch) {
            int off = ch * 32 + q * 8;
            short4v alo = *(const short4v*)&gS[w][r16][off];
            short4v ahi = *(const short4v*)&gS[w][r16][off + 4];
            short8 af = __builtin_shufflevector(alo, ahi, 0, 1, 2, 3, 4, 5, 6, 7);
            #pragma unroll
            for (int tt = 0; tt < 8; ++tt)
                acc[tt] = __builtin_amdgcn_mfma_f32_16x16x32_bf16(af, bfr[tt][ch], acc[tt], 0, 0, 0);
        }

        // epilogue: max_k(pe + xp[knn]) - xp[n], BN, residual add
        int i0 = idS[w][q * 4 + 0];
        int i1 = idS[w][q * 4 + 1];
        int i2 = idS[w][q * 4 + 2];
        int i3 = idS[w][q * 4 + 3];
        const float* xr0 = xp + (size_t)i0 * 128 + r16;
        const float* xr1 = xp + (size_t)i1 * 128 + r16;
        const float* xr2 = xp + (size_t)i2 * 128 + r16;
        const float* xr3 = xp + (size_t)i3 * 128 + r16;
        float keep0 = 0.f, keep1 = 0.f;
        #pragma unroll
        for (int tt = 0; tt < 8; ++tt) {
            int cb = tt * 16;
            float v0 = acc[tt].x + xr0[cb];
            float v1 = acc[tt].y + xr1[cb];
            float v2 = acc[tt].z + xr2[cb];
            float v3 = acc[tt].w + xr3[cb];
            float mx = fmaxf(fmaxf(v0, v1), fmaxf(v2, v3));
            mx = fmaxf(mx, __shfl_xor(mx, 16));
            mx = fmaxf(mx, __shfl_xor(mx, 32));
            if (tt == q)     keep0 = mx;
            if (tt == q + 4) keep1 = mx;
        }
        size_t base = (size_t)n * 128;
        float y0 = keep0 + b3b0 - xp[base + l];
        float y1 = keep1 + b3b1 - xp[base + l + 64];
        feat[base + l]      += y0 * lg0 + lb0;
        feat[base + l + 64] += y1 * lg1 + lb1;
    }
}

// ---------------------------------------------------------------------------
// Postproj: out = BN(feat) @ pp_w (128->256). Unchanged (R1).
// ---------------------------------------------------------------------------
__global__ __launch_bounds__(256) void postproj_kernel(
    float* __restrict__ out, const float* __restrict__ feat,
    const float* __restrict__ g, const float* __restrict__ b, const float* __restrict__ W)
{
    int n0 = blockIdx.x * 4;
    int t = threadIdx.x;
    __shared__ __align__(16) float fin[4][128];
    for (int v = t; v < 512; v += 256) {
        int c = v & 127;
        fin[v >> 7][c] = feat[(size_t)n0 * 128 + v] * (g[c] * BN_RSQ) + b[c];
    }
    __syncthreads();
    float acc[4] = {0.f, 0.f, 0.f, 0.f};
    for (int j = 0; j < 128; j += 4) {
        float wa = W[(j + 0) * 256 + t];
        float wb = W[(j + 1) * 256 + t];
        float wc = W[(j + 2) * 256 + t];
        float wd = W[(j + 3) * 256 + t];
        #pragma unroll
        for (int p = 0; p < 4; ++p) {
            float4 f = *(const float4*)&fin[p][j];
            acc[p] += f.x * wa + f.y * wb + f.z * wc + f.w * wd;
        }
    }
    #pragma unroll
    for (int p = 0; p < 4; ++p) out[(size_t)(n0 + p) * 256 + t] = acc[p];
}

// ---------------------------------------------------------------------------
extern "C" void kernel_launch(void* const* d_in, const int* in_sizes, int n_in,
                              void* d_out, int out_size, void* d_ws, size_t ws_size,
                              hipStream_t stream) {
    const float* x       = (const float*)d_in[0];
    const float* xyz     = (const float*)d_in[1];
    const float* g_pos   = (const float*)d_in[2];
    const float* ne_w1   = (const float*)d_in[3];
    const float* ne_g1   = (const float*)d_in[4];
    const float* ne_b1   = (const float*)d_in[5];
    const float* ne_w2   = (const float*)d_in[6];
    const float* ne_g2   = (const float*)d_in[7];
    const float* ne_b2   = (const float*)d_in[8];
    const float* ne_w3   = (const float*)d_in[9];
    const float* nbr_g   = (const float*)d_in[10];
    const float* nbr_b   = (const float*)d_in[11];
    const float* gpe_w   = (const float*)d_in[12];
    const float* bm_w1   = (const float*)d_in[13];
    const float* bm_b1   = (const float*)d_in[14];
    const float* bm_w2   = (const float*)d_in[15];
    const float* bm_g    = (const float*)d_in[16];
    const float* bm_b    = (const float*)d_in[17];
    const float* lfa_proj = (const float*)d_in[18];
    const float* lfa_g   = (const float*)d_in[19];
    const float* lfa_b   = (const float*)d_in[20];
    const float* nca_w1  = (const float*)d_in[21];
    const float* nca_b1  = (const float*)d_in[22];
    const float* nca_w2  = (const float*)d_in[23];
    const float* nca_b2  = (const float*)d_in[24];
    const float* nca_w3a = (const float*)d_in[25];
    const float* nca_b3a = (const float*)d_in[26];
    const float* nca_w3b = (const float*)d_in[27];
    const float* nca_b3b = (const float*)d_in[28];
    const float* m_w1    = (const float*)d_in[29];
    const float* m_b1    = (const float*)d_in[30];
    const float* m_w2    = (const float*)d_in[31];
    const float* m_g     = (const float*)d_in[32];
    const float* m_b     = (const float*)d_in[33];
    const float* pp_g    = (const float*)d_in[34];
    const float* pp_b    = (const float*)d_in[35];
    const float* pp_w    = (const float*)d_in[36];
    const int*   knn     = (const int*)d_in[37];

    float* ws    = (float*)d_ws;
    float* dxyz  = ws;                                   // N*48
    float* feat  = dxyz + (size_t)NPTS * 48;             // N*128
    float* xp    = feat + (size_t)NPTS * 128;            // N*128
    float* Weff  = xp + (size_t)NPTS * 128;              // 4*384
    float* cbias = Weff + 4 * 384;                       // 4*128
    unsigned short* w3bPack = (unsigned short*)(cbias + 4 * 128);   // 65536 shorts
    unsigned short* nePack  = w3bPack + 65536;                      // 4096 shorts
    float* out   = (float*)d_out;

    hipLaunchKernelGGL(precompute_kernel, dim3(4), dim3(128), 0, stream,
                       nca_w1, nca_b1, nca_w2, nca_b2, nca_w3a, nca_b3a, Weff, cbias);
    hipLaunchKernelGGL(pack_kernel, dim3(136), dim3(64), 0, stream,
                       nca_w3b, ne_w3, w3bPack, nePack);
    hipLaunchKernelGGL(nbr_embed_mfma, dim3(NPTS / NBR_P), dim3(128), 0, stream,
                       x, xyz, g_pos, knn,
                       ne_w1, ne_g1, ne_b1, ne_w2, ne_g2, ne_b2, nePack,
                       nbr_g, nbr_b, gpe_w, dxyz, feat);
    hipLaunchKernelGGL(mlp_res_kernel, dim3(NPTS / 4), dim3(256), 0, stream,
                       feat, bm_w1, bm_b1, bm_w2, bm_g, bm_b);
    for (int i = 0; i < 4; ++i) {
        hipLaunchKernelGGL(linear128_kernel, dim3(NPTS / 4), dim3(128), 0, stream,
                           xp, feat, lfa_proj + (size_t)i * 128 * 128);
        hipLaunchKernelGGL(lfa_mfma_kernel, dim3(NPTS / (4 * LFA_P)), dim3(256), 0, stream,
                           feat, xp, dxyz, knn,
                           nca_w1 + (size_t)i * 192, nca_b1 + (size_t)i * 64,
                           nca_w3a + (size_t)i * 16384 + 64 * 128,
                           Weff + (size_t)i * 384, cbias + (size_t)i * 128,
                           w3bPack + (size_t)i * 16384,
                           nca_b3b + (size_t)i * 128,
                           lfa_g + (size_t)i * 128, lfa_b + (size_t)i * 128);
        if (i & 1) {
            int j = i >> 1;
            hipLaunchKernelGGL(mlp_res_kernel, dim3(NPTS / 4), dim3(256), 0, stream,
                               feat, m_w1 + (size_t)j * 128 * 256, m_b1 + (size_t)j * 256,
                               m_w2 + (size_t)j * 256 * 128, m_g + (size_t)j * 128,
                               m_b + (size_t)j * 128);
        }
    }
    hipLaunchKernelGGL(postproj_kernel, dim3(NPTS / 4), dim3(256), 0, stream,
                       out, feat, pp_g, pp_b, pp_w);
}

// Round 3
// 631.602 us; speedup vs baseline: 4.2372x; 2.3304x over previous
//
#include <hip/hip_runtime.h>
#include <math.h>

#define NPTS 32768
#define BN_RSQ 0.9999950000374997f
#define NBR_P 8

typedef __attribute__((ext_vector_type(8))) short short8;
typedef __attribute__((ext_vector_type(4))) short short4v;
typedef __attribute__((ext_vector_type(4))) float floatx4;

// fast GELU: x * sigmoid(x*(1.5957691 + 0.07135685 x^2))  (tanh-form identity)
__device__ __forceinline__ float gelu_f(float v) {
    float c = v * v;
    float z = v * (1.5957691f + 0.07135685f * c);
    float s = __builtin_amdgcn_rcpf(1.0f + __expf(-z));
    return v * s;
}
__device__ __forceinline__ unsigned short f2bf(float f) {
    unsigned u = __float_as_uint(f);
    u += 0x7fffu + ((u >> 16) & 1u);
    return (unsigned short)(u >> 16);
}
__device__ __forceinline__ float bf2f(unsigned u) {
    return __uint_as_float(u << 16);
}

// ---------------------------------------------------------------------------
// Folded matrices per depth: Weff[i] = w1@w2@w3a_top (3x128),
// cbias[i] = (b1@w2 + b2)@w3a_top + b3a (128)
// ---------------------------------------------------------------------------
__global__ __launch_bounds__(128) void precompute_kernel(
    const float* __restrict__ nca_w1, const float* __restrict__ nca_b1,
    const float* __restrict__ nca_w2, const float* __restrict__ nca_b2,
    const float* __restrict__ nca_w3a, const float* __restrict__ nca_b3a,
    float* __restrict__ Weff, float* __restrict__ cbias)
{
    int i = blockIdx.x;
    int t = threadIdx.x;
    const float* w1 = nca_w1 + i * 3 * 64;
    const float* b1 = nca_b1 + i * 64;
    const float* w2 = nca_w2 + i * 64 * 64;
    const float* b2 = nca_b2 + i * 64;
    const float* w3a = nca_w3a + i * 128 * 128;
    const float* b3a = nca_b3a + i * 128;

    __shared__ float u[3][64];
    __shared__ float v[64];
    if (t < 64) {
        for (int r = 0; r < 3; ++r) {
            float s = 0.f;
            for (int m = 0; m < 64; ++m) s += w1[r * 64 + m] * w2[m * 64 + t];
            u[r][t] = s;
        }
        float s = 0.f;
        for (int m = 0; m < 64; ++m) s += b1[m] * w2[m * 64 + t];
        v[t] = s + b2[t];
    }
    __syncthreads();
    for (int r = 0; r < 3; ++r) {
        float s = 0.f;
        for (int m = 0; m < 64; ++m) s += u[r][m] * w3a[m * 128 + t];
        Weff[i * 384 + r * 128 + t] = s;
    }
    {
        float s = 0.f;
        for (int m = 0; m < 64; ++m) s += v[m] * w3a[m * 128 + t];
        cbias[i * 128 + t] = s + b3a[t];
    }
}

// ---------------------------------------------------------------------------
// Generic B-fragment packer. One block = one (tile,chunk) fragment of one
// weight. Frag layout: dst[(tile*Kc + chunk)*64 + lane][j] =
//   bf16( src[(chunk*32 + (lane>>4)*8 + j)*C + tile*16 + (lane&15)] )
// ---------------------------------------------------------------------------
__global__ __launch_bounds__(64) void pack_all(
    const float* __restrict__ bm_w1, const float* __restrict__ bm_w2,
    const float* __restrict__ m_w1, const float* __restrict__ m_w2,
    const float* __restrict__ lfa_proj, const float* __restrict__ pp_w,
    const float* __restrict__ nca_w3a, const float* __restrict__ nca_w3b,
    const float* __restrict__ ne_w3,
    unsigned short* __restrict__ P_bm1, unsigned short* __restrict__ P_bm2,
    unsigned short* __restrict__ P_m1, unsigned short* __restrict__ P_m2,
    unsigned short* __restrict__ P_proj, unsigned short* __restrict__ P_pp,
    unsigned short* __restrict__ P_w3a, unsigned short* __restrict__ P_w3b,
    unsigned short* __restrict__ P_ne)
{
    int b = blockIdx.x, l = threadIdx.x;
    const float* src; unsigned short* dst; int K, C, fb;
    if (b < 64)       { src = bm_w1; dst = P_bm1; K = 128; C = 256; fb = b; }
    else if (b < 128) { src = bm_w2; dst = P_bm2; K = 256; C = 128; fb = b - 64; }
    else if (b < 256) { int i = (b - 128) >> 6; src = m_w1 + i * 32768; dst = P_m1 + i * 32768; K = 128; C = 256; fb = (b - 128) & 63; }
    else if (b < 384) { int i = (b - 256) >> 6; src = m_w2 + i * 32768; dst = P_m2 + i * 32768; K = 256; C = 128; fb = (b - 256) & 63; }
    else if (b < 512) { int i = (b - 384) >> 5; src = lfa_proj + i * 16384; dst = P_proj + i * 16384; K = 128; C = 128; fb = (b - 384) & 31; }
    else if (b < 576) { src = pp_w; dst = P_pp; K = 128; C = 256; fb = b - 512; }
    else if (b < 640) { int i = (b - 576) >> 4; src = nca_w3a + i * 16384 + 64 * 128; dst = P_w3a + i * 8192; K = 64; C = 128; fb = (b - 576) & 15; }
    else if (b < 768) { int i = (b - 640) >> 5; src = nca_w3b + i * 16384; dst = P_w3b + i * 16384; K = 128; C = 128; fb = (b - 640) & 31; }
    else              { src = ne_w3; dst = P_ne; K = 32; C = 128; fb = b - 768; }
    int Kc = K >> 5;
    int tile = fb / Kc, chunk = fb % Kc;
    unsigned short* o = dst + ((size_t)fb * 64 + l) * 8;
    #pragma unroll
    for (int j = 0; j < 8; ++j) {
        int kk = chunk * 32 + (l >> 4) * 8 + j;
        int nn = tile * 16 + (l & 15);
        o[j] = f2bf(src[kk * C + nn]);
    }
}

// ---------------------------------------------------------------------------
// Neighbor embedding (R2 structure, fast gelu).
// ---------------------------------------------------------------------------
__global__ __launch_bounds__(128) void nbr_embed_mfma(
    const float* __restrict__ x, const float* __restrict__ xyz,
    const float* __restrict__ g_pos, const int* __restrict__ knn,
    const float* __restrict__ ne_w1, const float* __restrict__ ne_g1, const float* __restrict__ ne_b1,
    const float* __restrict__ ne_w2, const float* __restrict__ ne_g2, const float* __restrict__ ne_b2,
    const unsigned short* __restrict__ nePack,
    const float* __restrict__ nbr_g, const float* __restrict__ nbr_b,
    const float* __restrict__ gpe_w,
    float* __restrict__ dxyz_out, float* __restrict__ feat)
{
    int t = threadIdx.x;
    int h = t >> 6, l = t & 63;
    int k = t >> 3, r = t & 7;
    int q = l >> 4, r16 = l & 15;
    int cown = h * 64 + l;

    __shared__ __align__(16) float nbS[16][12];
    __shared__ float h1S[16][17];
    __shared__ __align__(16) unsigned short h2S[16][40];
    __shared__ __align__(16) float gpS[64];
    __shared__ int idS[16];

    short8 bf[4];
    #pragma unroll
    for (int tt = 0; tt < 4; ++tt)
        bf[tt] = ((const short8*)nePack)[(h * 4 + tt) * 64 + l];

    float w1a[10], w1b[10];
    #pragma unroll
    for (int j = 0; j < 10; ++j) { w1a[j] = ne_w1[j * 16 + r]; w1b[j] = ne_w1[j * 16 + r + 8]; }
    float g1a = ne_g1[r] * BN_RSQ,     b1a = ne_b1[r];
    float g1b = ne_g1[r + 8] * BN_RSQ, b1b = ne_b1[r + 8];
    float4 w2c[16];
    #pragma unroll
    for (int j = 0; j < 16; ++j) w2c[j] = *(const float4*)&ne_w2[j * 32 + r * 4];
    float4 g2v = *(const float4*)&ne_g2[r * 4];
    g2v.x *= BN_RSQ; g2v.y *= BN_RSQ; g2v.z *= BN_RSQ; g2v.w *= BN_RSQ;
    float4 b2v = *(const float4*)&ne_b2[r * 4];
    float bng = nbr_g[cown] * BN_RSQ, bnb = nbr_b[cown];

    for (int it = 0; it < NBR_P; ++it) {
        int n = blockIdx.x * NBR_P + it;
        if (t < 16) idS[t] = knn[n * 16 + t];
        if (t < 64) gpS[t] = g_pos[(size_t)n * 64 + t];
        __syncthreads();

        int id = idS[k];
        if (r < 3) {
            float d = xyz[(size_t)id * 3 + r] - xyz[(size_t)n * 3 + r];
            nbS[k][r] = d;
            dxyz_out[(size_t)n * 48 + k * 3 + r] = d;
        } else {
            nbS[k][r] = x[(size_t)id * 7 + (r - 3)];
        }
        if (r < 2) nbS[k][8 + r] = x[(size_t)id * 7 + 5 + r];

        float s0 = 0.f, s1 = 0.f;
        #pragma unroll
        for (int j = 0; j < 10; ++j) {
            float nv = nbS[k][j];
            s0 += nv * w1a[j];
            s1 += nv * w1b[j];
        }
        h1S[k][r]     = gelu_f(s0 * g1a + b1a);
        h1S[k][r + 8] = gelu_f(s1 * g1b + b1b);

        float a0 = 0.f, a1 = 0.f, a2 = 0.f, a3 = 0.f;
        #pragma unroll
        for (int j = 0; j < 16; ++j) {
            float hv = h1S[k][j];
            a0 += hv * w2c[j].x; a1 += hv * w2c[j].y;
            a2 += hv * w2c[j].z; a3 += hv * w2c[j].w;
        }
        a0 = gelu_f(a0 * g2v.x + b2v.x);
        a1 = gelu_f(a1 * g2v.y + b2v.y);
        a2 = gelu_f(a2 * g2v.z + b2v.z);
        a3 = gelu_f(a3 * g2v.w + b2v.w);
        {
            unsigned lo = (unsigned)f2bf(a0) | ((unsigned)f2bf(a1) << 16);
            unsigned hi = (unsigned)f2bf(a2) | ((unsigned)f2bf(a3) << 16);
            unsigned* h2p = (unsigned*)&h2S[k][r * 4];
            h2p[0] = lo; h2p[1] = hi;
        }
        __syncthreads();

        short8 af = *(const short8*)&h2S[r16][q * 8];
        floatx4 z4 = {0.f, 0.f, 0.f, 0.f};
        floatx4 acc[4];
        #pragma unroll
        for (int tt = 0; tt < 4; ++tt)
            acc[tt] = __builtin_amdgcn_mfma_f32_16x16x32_bf16(af, bf[tt], z4, 0, 0, 0);

        float gp = 0.f;
        #pragma unroll 4
        for (int j = 0; j < 64; j += 4) {
            float4 g4 = *(const float4*)&gpS[j];
            gp += g4.x * gpe_w[(j + 0) * 128 + cown];
            gp += g4.y * gpe_w[(j + 1) * 128 + cown];
            gp += g4.z * gpe_w[(j + 2) * 128 + cown];
            gp += g4.w * gpe_w[(j + 3) * 128 + cown];
        }

        float keep = 0.f;
        #pragma unroll
        for (int tt = 0; tt < 4; ++tt) {
            float mx = fmaxf(fmaxf(acc[tt].x, acc[tt].y), fmaxf(acc[tt].z, acc[tt].w));
            mx = fmaxf(mx, __shfl_xor(mx, 16));
            mx = fmaxf(mx, __shfl_xor(mx, 32));
            if (tt == q) keep = mx;
        }
        feat[(size_t)n * 128 + cown] = keep * bng + bnb + gp;
        __syncthreads();
    }
}

// ---------------------------------------------------------------------------
// Residual MLP via MFMA: feat += BN(GELU(feat@w1+b1)@w2, g, b).
// Block 256 = 4 waves, 16 points/iter, 4 iters (64 points/block), grid 512.
// ---------------------------------------------------------------------------
__global__ __launch_bounds__(256, 2) void mlp_mfma(
    float* __restrict__ feat,
    const unsigned short* __restrict__ P1, const float* __restrict__ b1,
    const unsigned short* __restrict__ P2,
    const float* __restrict__ g, const float* __restrict__ b)
{
    int t = threadIdx.x, w = t >> 6, l = t & 63;
    int q = l >> 4, r16 = l & 15;
    __shared__ __align__(16) unsigned short aS[16][136];
    __shared__ __align__(16) unsigned short hS[16][264];
    __shared__ __align__(16) float fS[16][132];

    const short8* B1 = (const short8*)P1;   // 16 tiles x 4 chunks
    const short8* B2 = (const short8*)P2;   // 8 tiles x 8 chunks
    short8 b1f[4][4];
    #pragma unroll
    for (int nt = 0; nt < 4; ++nt)
        #pragma unroll
        for (int ch = 0; ch < 4; ++ch)
            b1f[nt][ch] = B1[((w * 4 + nt) * 4 + ch) * 64 + l];
    short8 b2f[2][8];
    #pragma unroll
    for (int nt = 0; nt < 2; ++nt)
        #pragma unroll
        for (int ch = 0; ch < 8; ++ch)
            b2f[nt][ch] = B2[((w * 2 + nt) * 8 + ch) * 64 + l];
    float bb1[4];
    #pragma unroll
    for (int nt = 0; nt < 4; ++nt) bb1[nt] = b1[w * 64 + nt * 16 + r16];
    float gg[2], bb[2];
    #pragma unroll
    for (int nt = 0; nt < 2; ++nt) {
        int c = w * 32 + nt * 16 + r16;
        gg[nt] = g[c] * BN_RSQ; bb[nt] = b[c];
    }

    for (int itc = 0; itc < 4; ++itc) {
        int n0 = blockIdx.x * 64 + itc * 16;
        {
            int row = t >> 4, c8 = (t & 15) * 8;
            float4 fa = *(const float4*)&feat[(size_t)(n0 + row) * 128 + c8];
            float4 fb4 = *(const float4*)&feat[(size_t)(n0 + row) * 128 + c8 + 4];
            *(float4*)&fS[row][c8] = fa;
            *(float4*)&fS[row][c8 + 4] = fb4;
            unsigned u0 = (unsigned)f2bf(fa.x) | ((unsigned)f2bf(fa.y) << 16);
            unsigned u1 = (unsigned)f2bf(fa.z) | ((unsigned)f2bf(fa.w) << 16);
            unsigned u2 = (unsigned)f2bf(fb4.x) | ((unsigned)f2bf(fb4.y) << 16);
            unsigned u3 = (unsigned)f2bf(fb4.z) | ((unsigned)f2bf(fb4.w) << 16);
            *(uint4*)&aS[row][c8] = make_uint4(u0, u1, u2, u3);
        }
        __syncthreads();

        floatx4 z4 = {0.f, 0.f, 0.f, 0.f};
        floatx4 acc1[4];
        #pragma unroll
        for (int nt = 0; nt < 4; ++nt) acc1[nt] = z4;
        #pragma unroll
        for (int ch = 0; ch < 4; ++ch) {
            short8 af = *(const short8*)&aS[r16][ch * 32 + q * 8];
            #pragma unroll
            for (int nt = 0; nt < 4; ++nt)
                acc1[nt] = __builtin_amdgcn_mfma_f32_16x16x32_bf16(af, b1f[nt][ch], acc1[nt], 0, 0, 0);
        }
        #pragma unroll
        for (int nt = 0; nt < 4; ++nt) {
            int c = w * 64 + nt * 16 + r16;
            #pragma unroll
            for (int rg = 0; rg < 4; ++rg)
                hS[q * 4 + rg][c] = f2bf(gelu_f(acc1[nt][rg] + bb1[nt]));
        }
        __syncthreads();

        floatx4 acc2[2];
        #pragma unroll
        for (int nt = 0; nt < 2; ++nt) acc2[nt] = z4;
        #pragma unroll
        for (int ch = 0; ch < 8; ++ch) {
            short8 af = *(const short8*)&hS[r16][ch * 32 + q * 8];
            #pragma unroll
            for (int nt = 0; nt < 2; ++nt)
                acc2[nt] = __builtin_amdgcn_mfma_f32_16x16x32_bf16(af, b2f[nt][ch], acc2[nt], 0, 0, 0);
        }
        #pragma unroll
        for (int nt = 0; nt < 2; ++nt) {
            int c = w * 32 + nt * 16 + r16;
            #pragma unroll
            for (int rg = 0; rg < 4; ++rg) {
                int row = q * 4 + rg;
                feat[(size_t)(n0 + row) * 128 + c] = fS[row][c] + acc2[nt][rg] * gg[nt] + bb[nt];
            }
        }
        __syncthreads();
    }
}

// ---------------------------------------------------------------------------
// xp = feat @ proj (128->128), bf16 output. Same skeleton.
// ---------------------------------------------------------------------------
__global__ __launch_bounds__(256) void linear_mfma(
    const float* __restrict__ feat, const unsigned short* __restrict__ P,
    unsigned short* __restrict__ xp)
{
    int t = threadIdx.x, w = t >> 6, l = t & 63;
    int q = l >> 4, r16 = l & 15;
    __shared__ __align__(16) unsigned short aS[16][136];
    const short8* B = (const short8*)P;     // 8 tiles x 4 chunks
    short8 bf[2][4];
    #pragma unroll
    for (int nt = 0; nt < 2; ++nt)
        #pragma unroll
        for (int ch = 0; ch < 4; ++ch)
            bf[nt][ch] = B[((w * 2 + nt) * 4 + ch) * 64 + l];

    for (int itc = 0; itc < 4; ++itc) {
        int n0 = blockIdx.x * 64 + itc * 16;
        {
            int row = t >> 4, c8 = (t & 15) * 8;
            float4 fa = *(const float4*)&feat[(size_t)(n0 + row) * 128 + c8];
            float4 fb4 = *(const float4*)&feat[(size_t)(n0 + row) * 128 + c8 + 4];
            unsigned u0 = (unsigned)f2bf(fa.x) | ((unsigned)f2bf(fa.y) << 16);
            unsigned u1 = (unsigned)f2bf(fa.z) | ((unsigned)f2bf(fa.w) << 16);
            unsigned u2 = (unsigned)f2bf(fb4.x) | ((unsigned)f2bf(fb4.y) << 16);
            unsigned u3 = (unsigned)f2bf(fb4.z) | ((unsigned)f2bf(fb4.w) << 16);
            *(uint4*)&aS[row][c8] = make_uint4(u0, u1, u2, u3);
        }
        __syncthreads();
        floatx4 z4 = {0.f, 0.f, 0.f, 0.f};
        floatx4 acc[2];
        #pragma unroll
        for (int nt = 0; nt < 2; ++nt) acc[nt] = z4;
        #pragma unroll
        for (int ch = 0; ch < 4; ++ch) {
            short8 af = *(const short8*)&aS[r16][ch * 32 + q * 8];
            #pragma unroll
            for (int nt = 0; nt < 2; ++nt)
                acc[nt] = __builtin_amdgcn_mfma_f32_16x16x32_bf16(af, bf[nt][ch], acc[nt], 0, 0, 0);
        }
        #pragma unroll
        for (int nt = 0; nt < 2; ++nt) {
            int c = w * 32 + nt * 16 + r16;
            #pragma unroll
            for (int rg = 0; rg < 4; ++rg)
                xp[(size_t)(n0 + q * 4 + rg) * 128 + c] = f2bf(acc[nt][rg]);
        }
        __syncthreads();
    }
}

// ---------------------------------------------------------------------------
// Postproj: out = BN(feat) @ pp_w (128->256), fp32 out.
// ---------------------------------------------------------------------------
__global__ __launch_bounds__(256) void postproj_mfma(
    float* __restrict__ out, const float* __restrict__ feat,
    const float* __restrict__ g, const float* __restrict__ b,
    const unsigned short* __restrict__ P)
{
    int t = threadIdx.x, w = t >> 6, l = t & 63;
    int q = l >> 4, r16 = l & 15;
    __shared__ __align__(16) unsigned short aS[16][136];
    const short8* B = (const short8*)P;     // 16 tiles x 4 chunks
    short8 bf[4][4];
    #pragma unroll
    for (int nt = 0; nt < 4; ++nt)
        #pragma unroll
        for (int ch = 0; ch < 4; ++ch)
            bf[nt][ch] = B[((w * 4 + nt) * 4 + ch) * 64 + l];

    for (int itc = 0; itc < 4; ++itc) {
        int n0 = blockIdx.x * 64 + itc * 16;
        {
            int row = t >> 4, c8 = (t & 15) * 8;
            const float* fp = &feat[(size_t)(n0 + row) * 128 + c8];
            float4 fa = *(const float4*)fp;
            float4 fb4 = *(const float4*)(fp + 4);
            float4 ga = *(const float4*)&g[c8], gb4 = *(const float4*)&g[c8 + 4];
            float4 ba = *(const float4*)&b[c8], bb4 = *(const float4*)&b[c8 + 4];
            unsigned u0 = (unsigned)f2bf(fa.x * ga.x * BN_RSQ + ba.x) | ((unsigned)f2bf(fa.y * ga.y * BN_RSQ + ba.y) << 16);
            unsigned u1 = (unsigned)f2bf(fa.z * ga.z * BN_RSQ + ba.z) | ((unsigned)f2bf(fa.w * ga.w * BN_RSQ + ba.w) << 16);
            unsigned u2 = (unsigned)f2bf(fb4.x * gb4.x * BN_RSQ + bb4.x) | ((unsigned)f2bf(fb4.y * gb4.y * BN_RSQ + bb4.y) << 16);
            unsigned u3 = (unsigned)f2bf(fb4.z * gb4.z * BN_RSQ + bb4.z) | ((unsigned)f2bf(fb4.w * gb4.w * BN_RSQ + bb4.w) << 16);
            *(uint4*)&aS[row][c8] = make_uint4(u0, u1, u2, u3);
        }
        __syncthreads();
        floatx4 z4 = {0.f, 0.f, 0.f, 0.f};
        floatx4 acc[4];
        #pragma unroll
        for (int nt = 0; nt < 4; ++nt) acc[nt] = z4;
        #pragma unroll
        for (int ch = 0; ch < 4; ++ch) {
            short8 af = *(const short8*)&aS[r16][ch * 32 + q * 8];
            #pragma unroll
            for (int nt = 0; nt < 4; ++nt)
                acc[nt] = __builtin_amdgcn_mfma_f32_16x16x32_bf16(af, bf[nt][ch], acc[nt], 0, 0, 0);
        }
        #pragma unroll
        for (int nt = 0; nt < 4; ++nt) {
            int c = w * 64 + nt * 16 + r16;
            #pragma unroll
            for (int rg = 0; rg < 4; ++rg)
                out[(size_t)(n0 + q * 4 + rg) * 256 + c] = acc[nt][rg];
        }
        __syncthreads();
    }
}

// ---------------------------------------------------------------------------
// LFA v3. Block 256 = 4 independent waves (zero barriers). Each wave: 16
// points. p_local -> batched tv GEMM (16 MFMAs) -> per point: fast-GELU(a)
// to LDS bf16 -> 32 MFMAs -> fused bf16-gather + max + BN epilogue.
// ---------------------------------------------------------------------------
__global__ __launch_bounds__(256, 2) void lfa_mfma2(
    float* __restrict__ feat, const unsigned short* __restrict__ xpb,
    const float* __restrict__ dxyz, const int* __restrict__ knn,
    const float* __restrict__ w1, const float* __restrict__ b1,
    const unsigned short* __restrict__ P_w3a, const float* __restrict__ Weff,
    const float* __restrict__ cbias, const unsigned short* __restrict__ P_w3b,
    const float* __restrict__ b3b,
    const float* __restrict__ lg, const float* __restrict__ lb)
{
    int w = threadIdx.x >> 6, l = threadIdx.x & 63;
    int q = l >> 4, r16 = l & 15;

    __shared__ __align__(16) float dxS[4][16][64];
    __shared__ __align__(16) unsigned short plA[4][16][72];
    __shared__ __align__(16) unsigned short tvS[4][16][136];
    __shared__ __align__(16) unsigned short gS[4][16][136];
    __shared__ int idS[4][256];

    int nbase = blockIdx.x * 64 + w * 16;

    #pragma unroll
    for (int i = 0; i < 4; ++i)
        idS[w][i * 64 + l] = knn[(size_t)nbase * 16 + i * 64 + l];
    #pragma unroll
    for (int i = 0; i < 12; ++i) {
        int gI = i * 64 + l;                 // 0..767
        int p = gI / 48, rr = gI % 48;
        int k = rr / 3, d = rr - k * 3;
        dxS[w][p][k * 4 + d] = dxyz[(size_t)nbase * 48 + gI];
    }

    // w3b fragments in registers (128 VGPR)
    short8 bfr[8][4];
    {
        const short8* bp = (const short8*)P_w3b;
        #pragma unroll
        for (int tt = 0; tt < 8; ++tt)
            #pragma unroll
            for (int ch = 0; ch < 4; ++ch)
                bfr[tt][ch] = bp[(tt * 4 + ch) * 64 + l];
    }
    int c0 = 2 * l;
    float2 we0 = *(const float2*)&Weff[c0];
    float2 we1 = *(const float2*)&Weff[128 + c0];
    float2 we2 = *(const float2*)&Weff[256 + c0];
    float w1r0 = w1[l], w1r1 = w1[64 + l], w1r2 = w1[128 + l], b1l = b1[l];
    float b3b0 = b3b[l], b3b1 = b3b[l + 64];
    float lg0 = lg[l] * BN_RSQ, lg1 = lg[l + 64] * BN_RSQ;
    float lb0 = lb[l], lb1 = lb[l + 64];

    // p_local for 16 points (lane l owns hidden dim l)
    for (int p = 0; p < 16; ++p) {
        float m = -1e30f;
        #pragma unroll
        for (int k = 0; k < 16; ++k) {
            float4 d4 = *(const float4*)&dxS[w][p][k * 4];
            m = fmaxf(m, b1l + d4.x * w1r0 + d4.y * w1r1 + d4.z * w1r2);
        }
        plA[w][p][l] = f2bf(m);
    }

    // tv = cbias + pl @ w3a_bot : [16x64] @ [64x128] -> tvS (bf16)
    {
        floatx4 z4 = {0.f, 0.f, 0.f, 0.f};
        floatx4 tacc[8];
        #pragma unroll
        for (int tt = 0; tt < 8; ++tt) tacc[tt] = z4;
        const short8* bpA = (const short8*)P_w3a;
        #pragma unroll
        for (int ch = 0; ch < 2; ++ch) {
            short8 af = *(const short8*)&plA[w][r16][ch * 32 + q * 8];
            #pragma unroll
            for (int tt = 0; tt < 8; ++tt)
                tacc[tt] = __builtin_amdgcn_mfma_f32_16x16x32_bf16(af, bpA[(tt * 2 + ch) * 64 + l], tacc[tt], 0, 0, 0);
        }
        #pragma unroll
        for (int tt = 0; tt < 8; ++tt) {
            float cb = cbias[tt * 16 + r16];
            #pragma unroll
            for (int rg = 0; rg < 4; ++rg)
                tvS[w][q * 4 + rg][tt * 16 + r16] = f2bf(tacc[tt][rg] + cb);
        }
    }

    for (int pp = 0; pp < 16; ++pp) {
        int n = nbase + pp;
        unsigned tvp = *(const unsigned*)&tvS[w][pp][c0];
        float tv0 = bf2f(tvp & 0xffffu), tv1 = bf2f(tvp >> 16);
        #pragma unroll
        for (int k = 0; k < 16; ++k) {
            float4 d4 = *(const float4*)&dxS[w][pp][k * 4];
            float s0 = tv0 + d4.x * we0.x + d4.y * we1.x + d4.z * we2.x;
            float s1 = tv1 + d4.x * we0.y + d4.y * we1.y + d4.z * we2.y;
            unsigned gw = (unsigned)f2bf(gelu_f(s0)) | ((unsigned)f2bf(gelu_f(s1)) << 16);
            *(unsigned*)&gS[w][k][c0] = gw;
        }

        floatx4 z4 = {0.f, 0.f, 0.f, 0.f};
        floatx4 acc[8];
        #pragma unroll
        for (int tt = 0; tt < 8; ++tt) acc[tt] = z4;
        #pragma unroll
        for (int ch = 0; ch < 4; ++ch) {
            short8 af = *(const short8*)&gS[w][r16][ch * 32 + q * 8];
            #pragma unroll
            for (int tt = 0; tt < 8; ++tt)
                acc[tt] = __builtin_amdgcn_mfma_f32_16x16x32_bf16(af, bfr[tt][ch], acc[tt], 0, 0, 0);
        }

        const int* idp = &idS[w][pp * 16];
        int i0 = idp[q * 4 + 0], i1 = idp[q * 4 + 1];
        int i2 = idp[q * 4 + 2], i3 = idp[q * 4 + 3];
        float keep0 = 0.f, keep1 = 0.f;
        #pragma unroll
        for (int tt = 0; tt < 8; ++tt) {
            int cb = tt * 16 + r16;
            float v0 = acc[tt].x + bf2f(xpb[(size_t)i0 * 128 + cb]);
            float v1 = acc[tt].y + bf2f(xpb[(size_t)i1 * 128 + cb]);
            float v2 = acc[tt].z + bf2f(xpb[(size_t)i2 * 128 + cb]);
            float v3 = acc[tt].w + bf2f(xpb[(size_t)i3 * 128 + cb]);
            float mx = fmaxf(fmaxf(v0, v1), fmaxf(v2, v3));
            mx = fmaxf(mx, __shfl_xor(mx, 16));
            mx = fmaxf(mx, __shfl_xor(mx, 32));
            if (tt == q)     keep0 = mx;
            if (tt == q + 4) keep1 = mx;
        }
        size_t base = (size_t)n * 128;
        float x0 = bf2f(xpb[base + l]), x1 = bf2f(xpb[base + l + 64]);
        feat[base + l]      += (keep0 + b3b0 - x0) * lg0 + lb0;
        feat[base + l + 64] += (keep1 + b3b1 - x1) * lg1 + lb1;
    }
}

// ---------------------------------------------------------------------------
extern "C" void kernel_launch(void* const* d_in, const int* in_sizes, int n_in,
                              void* d_out, int out_size, void* d_ws, size_t ws_size,
                              hipStream_t stream) {
    const float* x       = (const float*)d_in[0];
    const float* xyz     = (const float*)d_in[1];
    const float* g_pos   = (const float*)d_in[2];
    const float* ne_w1   = (const float*)d_in[3];
    const float* ne_g1   = (const float*)d_in[4];
    const float* ne_b1   = (const float*)d_in[5];
    const float* ne_w2   = (const float*)d_in[6];
    const float* ne_g2   = (const float*)d_in[7];
    const float* ne_b2   = (const float*)d_in[8];
    const float* ne_w3   = (const float*)d_in[9];
    const float* nbr_g   = (const float*)d_in[10];
    const float* nbr_b   = (const float*)d_in[11];
    const float* gpe_w   = (const float*)d_in[12];
    const float* bm_w1   = (const float*)d_in[13];
    const float* bm_b1   = (const float*)d_in[14];
    const float* bm_w2   = (const float*)d_in[15];
    const float* bm_g    = (const float*)d_in[16];
    const float* bm_b    = (const float*)d_in[17];
    const float* lfa_proj = (const float*)d_in[18];
    const float* lfa_g   = (const float*)d_in[19];
    const float* lfa_b   = (const float*)d_in[20];
    const float* nca_w1  = (const float*)d_in[21];
    const float* nca_b1  = (const float*)d_in[22];
    const float* nca_w2  = (const float*)d_in[23];
    const float* nca_b2  = (const float*)d_in[24];
    const float* nca_w3a = (const float*)d_in[25];
    const float* nca_b3a = (const float*)d_in[26];
    const float* nca_w3b = (const float*)d_in[27];
    const float* nca_b3b = (const float*)d_in[28];
    const float* m_w1    = (const float*)d_in[29];
    const float* m_b1    = (const float*)d_in[30];
    const float* m_w2    = (const float*)d_in[31];
    const float* m_g     = (const float*)d_in[32];
    const float* m_b     = (const float*)d_in[33];
    const float* pp_g    = (const float*)d_in[34];
    const float* pp_b    = (const float*)d_in[35];
    const float* pp_w    = (const float*)d_in[36];
    const int*   knn     = (const int*)d_in[37];

    float* ws    = (float*)d_ws;
    float* dxyz  = ws;                                   // N*48
    float* feat  = dxyz + (size_t)NPTS * 48;             // N*128
    float* Weff  = feat + (size_t)NPTS * 128;            // 1536
    float* cbias = Weff + 1536;                          // 512
    unsigned short* xpb    = (unsigned short*)(cbias + 512);    // N*128
    unsigned short* P_bm1  = xpb + (size_t)NPTS * 128;   // 32768
    unsigned short* P_bm2  = P_bm1 + 32768;              // 32768
    unsigned short* P_m1   = P_bm2 + 32768;              // 65536
    unsigned short* P_m2   = P_m1 + 65536;               // 65536
    unsigned short* P_proj = P_m2 + 65536;               // 65536
    unsigned short* P_pp   = P_proj + 65536;             // 32768
    unsigned short* P_w3a  = P_pp + 32768;               // 32768
    unsigned short* P_w3b  = P_w3a + 32768;              // 65536
    unsigned short* P_ne   = P_w3b + 65536;              // 4096
    float* out = (float*)d_out;

    hipLaunchKernelGGL(precompute_kernel, dim3(4), dim3(128), 0, stream,
                       nca_w1, nca_b1, nca_w2, nca_b2, nca_w3a, nca_b3a, Weff, cbias);
    hipLaunchKernelGGL(pack_all, dim3(776), dim3(64), 0, stream,
                       bm_w1, bm_w2, m_w1, m_w2, lfa_proj, pp_w, nca_w3a, nca_w3b, ne_w3,
                       P_bm1, P_bm2, P_m1, P_m2, P_proj, P_pp, P_w3a, P_w3b, P_ne);
    hipLaunchKernelGGL(nbr_embed_mfma, dim3(NPTS / NBR_P), dim3(128), 0, stream,
                       x, xyz, g_pos, knn,
                       ne_w1, ne_g1, ne_b1, ne_w2, ne_g2, ne_b2, P_ne,
                       nbr_g, nbr_b, gpe_w, dxyz, feat);
    hipLaunchKernelGGL(mlp_mfma, dim3(512), dim3(256), 0, stream,
                       feat, P_bm1, bm_b1, P_bm2, bm_g, bm_b);
    for (int i = 0; i < 4; ++i) {
        hipLaunchKernelGGL(linear_mfma, dim3(512), dim3(256), 0, stream,
                           feat, P_proj + (size_t)i * 16384, xpb);
        hipLaunchKernelGGL(lfa_mfma2, dim3(512), dim3(256), 0, stream,
                           feat, xpb, dxyz, knn,
                           nca_w1 + (size_t)i * 192, nca_b1 + (size_t)i * 64,
                           P_w3a + (size_t)i * 8192,
                           Weff + (size_t)i * 384, cbias + (size_t)i * 128,
                           P_w3b + (size_t)i * 16384,
                           nca_b3b + (size_t)i * 128,
                           lfa_g + (size_t)i * 128, lfa_b + (size_t)i * 128);
        if (i & 1) {
            int j = i >> 1;
            hipLaunchKernelGGL(mlp_mfma, dim3(512), dim3(256), 0, stream,
                               feat, P_m1 + (size_t)j * 32768, m_b1 + (size_t)j * 256,
                               P_m2 + (size_t)j * 32768, m_g + (size_t)j * 128,
                               m_b + (size_t)j * 128);
        }
    }
    hipLaunchKernelGGL(postproj_mfma, dim3(512), dim3(256), 0, stream,
                       out, feat, pp_g, pp_b, P_pp);
}

// Round 4
// 523.958 us; speedup vs baseline: 5.1077x; 1.2054x over previous
//
#include <hip/hip_runtime.h>
#include <math.h>

#define NPTS 32768
#define BN_RSQ 0.9999950000374997f

typedef __attribute__((ext_vector_type(8))) short short8;
typedef __attribute__((ext_vector_type(4))) float floatx4;

// fast GELU: x * sigmoid(x*(1.5957691 + 0.07135685 x^2))
__device__ __forceinline__ float gelu_f(float v) {
    float c = v * v;
    float z = v * (1.5957691f + 0.07135685f * c);
    float s = __builtin_amdgcn_rcpf(1.0f + __expf(-z));
    return v * s;
}
__device__ __forceinline__ unsigned short f2bf(float f) {
    unsigned u = __float_as_uint(f);
    u += 0x7fffu + ((u >> 16) & 1u);
    return (unsigned short)(u >> 16);
}
__device__ __forceinline__ float bf2f(unsigned u) {
    return __uint_as_float(u << 16);
}

// ---------------------------------------------------------------------------
// Folded matrices per depth: Weff[i] = w1@w2@w3a_top (3x128),
// cbias[i] = (b1@w2 + b2)@w3a_top + b3a (128)
// ---------------------------------------------------------------------------
__global__ __launch_bounds__(128) void precompute_kernel(
    const float* __restrict__ nca_w1, const float* __restrict__ nca_b1,
    const float* __restrict__ nca_w2, const float* __restrict__ nca_b2,
    const float* __restrict__ nca_w3a, const float* __restrict__ nca_b3a,
    float* __restrict__ Weff, float* __restrict__ cbias)
{
    int i = blockIdx.x;
    int t = threadIdx.x;
    const float* w1 = nca_w1 + i * 3 * 64;
    const float* b1 = nca_b1 + i * 64;
    const float* w2 = nca_w2 + i * 64 * 64;
    const float* b2 = nca_b2 + i * 64;
    const float* w3a = nca_w3a + i * 128 * 128;
    const float* b3a = nca_b3a + i * 128;

    __shared__ float u[3][64];
    __shared__ float v[64];
    if (t < 64) {
        for (int r = 0; r < 3; ++r) {
            float s = 0.f;
            for (int m = 0; m < 64; ++m) s += w1[r * 64 + m] * w2[m * 64 + t];
            u[r][t] = s;
        }
        float s = 0.f;
        for (int m = 0; m < 64; ++m) s += b1[m] * w2[m * 64 + t];
        v[t] = s + b2[t];
    }
    __syncthreads();
    for (int r = 0; r < 3; ++r) {
        float s = 0.f;
        for (int m = 0; m < 64; ++m) s += u[r][m] * w3a[m * 128 + t];
        Weff[i * 384 + r * 128 + t] = s;
    }
    {
        float s = 0.f;
        for (int m = 0; m < 64; ++m) s += v[m] * w3a[m * 128 + t];
        cbias[i * 128 + t] = s + b3a[t];
    }
}

// ---------------------------------------------------------------------------
// Generic B-fragment packer (bf16 MFMA B layout), with zero-pad beyond Kr and
// optional per-column gamma fold (gamma*BN_RSQ).
// ---------------------------------------------------------------------------
__global__ __launch_bounds__(64) void pack_all(
    const float* __restrict__ bm_w1, const float* __restrict__ bm_w2,
    const float* __restrict__ m_w1, const float* __restrict__ m_w2,
    const float* __restrict__ lfa_proj, const float* __restrict__ pp_w,
    const float* __restrict__ nca_w3a, const float* __restrict__ nca_w3b,
    const float* __restrict__ ne_w3, const float* __restrict__ gpe_w,
    const float* __restrict__ ne_w1, const float* __restrict__ ne_g1,
    const float* __restrict__ ne_w2, const float* __restrict__ ne_g2,
    unsigned short* __restrict__ P_bm1, unsigned short* __restrict__ P_bm2,
    unsigned short* __restrict__ P_m1, unsigned short* __restrict__ P_m2,
    unsigned short* __restrict__ P_proj, unsigned short* __restrict__ P_pp,
    unsigned short* __restrict__ P_w3a, unsigned short* __restrict__ P_w3b,
    unsigned short* __restrict__ P_ne3, unsigned short* __restrict__ P_gpe,
    unsigned short* __restrict__ P_ne1, unsigned short* __restrict__ P_ne2)
{
    int b = blockIdx.x, l = threadIdx.x;
    const float* src; unsigned short* dst; int K, C, fb; int Kr = 0;
    const float* fold = nullptr;
    if (b < 64)       { src = bm_w1; dst = P_bm1; K = 128; C = 256; fb = b; }
    else if (b < 128) { src = bm_w2; dst = P_bm2; K = 256; C = 128; fb = b - 64; }
    else if (b < 256) { int i = (b - 128) >> 6; src = m_w1 + i * 32768; dst = P_m1 + i * 32768; K = 128; C = 256; fb = (b - 128) & 63; }
    else if (b < 384) { int i = (b - 256) >> 6; src = m_w2 + i * 32768; dst = P_m2 + i * 32768; K = 256; C = 128; fb = (b - 256) & 63; }
    else if (b < 512) { int i = (b - 384) >> 5; src = lfa_proj + i * 16384; dst = P_proj + i * 16384; K = 128; C = 128; fb = (b - 384) & 31; }
    else if (b < 576) { src = pp_w; dst = P_pp; K = 128; C = 256; fb = b - 512; }
    else if (b < 640) { int i = (b - 576) >> 4; src = nca_w3a + i * 16384 + 64 * 128; dst = P_w3a + i * 8192; K = 64; C = 128; fb = (b - 576) & 15; }
    else if (b < 768) { int i = (b - 640) >> 5; src = nca_w3b + i * 16384; dst = P_w3b + i * 16384; K = 128; C = 128; fb = (b - 640) & 31; }
    else if (b < 776) { src = ne_w3; dst = P_ne3; K = 32; C = 128; fb = b - 768; }
    else if (b < 792) { src = gpe_w; dst = P_gpe; K = 64; C = 128; fb = b - 776; }
    else if (b == 792){ src = ne_w1; dst = P_ne1; K = 32; C = 16; fb = 0; Kr = 10; fold = ne_g1; }
    else              { src = ne_w2; dst = P_ne2; K = 32; C = 32; fb = b - 793; Kr = 16; fold = ne_g2; }
    if (Kr == 0) Kr = K;
    int Kc = K >> 5;
    int tile = fb / Kc, chunk = fb % Kc;
    unsigned short* o = dst + ((size_t)fb * 64 + l) * 8;
    #pragma unroll
    for (int j = 0; j < 8; ++j) {
        int kk = chunk * 32 + (l >> 4) * 8 + j;
        int nn = tile * 16 + (l & 15);
        float v = 0.f;
        if (kk < Kr) {
            v = src[kk * C + nn];
            if (fold) v *= fold[nn] * BN_RSQ;
        }
        o[j] = f2bf(v);
    }
}

// ---------------------------------------------------------------------------
// Neighbor embedding v2: 4 independent waves/block, zero barriers, all three
// layers MFMA (K-padded, gamma folded into packed weights). gpe moved out.
// grid 1024 x 256, 8 points/wave.
// ---------------------------------------------------------------------------
__global__ __launch_bounds__(256) void nbr_embed_v2(
    const float* __restrict__ x, const float* __restrict__ xyz,
    const int* __restrict__ knn,
    const float* __restrict__ ne_b1, const float* __restrict__ ne_b2,
    const unsigned short* __restrict__ P_ne1, const unsigned short* __restrict__ P_ne2,
    const unsigned short* __restrict__ P_ne3,
    const float* __restrict__ nbr_g, const float* __restrict__ nbr_b,
    float* __restrict__ dxyz_out, float* __restrict__ feat)
{
    int t = threadIdx.x, w = t >> 6, l = t & 63, q = l >> 4, r16 = l & 15;
    __shared__ __align__(16) unsigned short h1L[4][16][24];
    __shared__ __align__(16) unsigned short h2L[4][16][40];

    short8 B1 = ((const short8*)P_ne1)[l];
    short8 B2[2], B3[8];
    B2[0] = ((const short8*)P_ne2)[l];
    B2[1] = ((const short8*)P_ne2)[64 + l];
    #pragma unroll
    for (int tt = 0; tt < 8; ++tt) B3[tt] = ((const short8*)P_ne3)[tt * 64 + l];
    float b1r = ne_b1[r16];
    float b2r0 = ne_b2[r16], b2r1 = ne_b2[16 + r16];
    float bg0 = nbr_g[l] * BN_RSQ, bb0 = nbr_b[l];
    float bg1 = nbr_g[l + 64] * BN_RSQ, bb1 = nbr_b[l + 64];
    int nbase = blockIdx.x * 32 + w * 8;
    floatx4 z4 = {0.f, 0.f, 0.f, 0.f};

    for (int pp = 0; pp < 8; ++pp) {
        int n = nbase + pp;
        int id = knn[n * 16 + r16];
        float f0 = 0.f, f1 = 0.f, f2 = 0.f, f3 = 0.f, f4 = 0.f, f5 = 0.f, f6 = 0.f, f7 = 0.f;
        if (q == 0) {
            f0 = xyz[(size_t)id * 3 + 0] - xyz[(size_t)n * 3 + 0];
            f1 = xyz[(size_t)id * 3 + 1] - xyz[(size_t)n * 3 + 1];
            f2 = xyz[(size_t)id * 3 + 2] - xyz[(size_t)n * 3 + 2];
            dxyz_out[(size_t)n * 48 + r16 * 3 + 0] = f0;
            dxyz_out[(size_t)n * 48 + r16 * 3 + 1] = f1;
            dxyz_out[(size_t)n * 48 + r16 * 3 + 2] = f2;
            f3 = x[(size_t)id * 7 + 0]; f4 = x[(size_t)id * 7 + 1];
            f5 = x[(size_t)id * 7 + 2]; f6 = x[(size_t)id * 7 + 3];
            f7 = x[(size_t)id * 7 + 4];
        } else if (q == 1) {
            f0 = x[(size_t)id * 7 + 5]; f1 = x[(size_t)id * 7 + 6];
        }
        short8 a1;
        a1[0] = f2bf(f0); a1[1] = f2bf(f1); a1[2] = f2bf(f2); a1[3] = f2bf(f3);
        a1[4] = f2bf(f4); a1[5] = f2bf(f5); a1[6] = f2bf(f6); a1[7] = f2bf(f7);
        floatx4 c1 = __builtin_amdgcn_mfma_f32_16x16x32_bf16(a1, B1, z4, 0, 0, 0);
        #pragma unroll
        for (int rg = 0; rg < 4; ++rg)
            h1L[w][q * 4 + rg][r16] = f2bf(gelu_f(c1[rg] + b1r));

        short8 a2 = {0, 0, 0, 0, 0, 0, 0, 0};
        if (q < 2) a2 = *(const short8*)&h1L[w][r16][q * 8];
        #pragma unroll
        for (int nt = 0; nt < 2; ++nt) {
            floatx4 c2 = __builtin_amdgcn_mfma_f32_16x16x32_bf16(a2, B2[nt], z4, 0, 0, 0);
            float br = nt ? b2r1 : b2r0;
            #pragma unroll
            for (int rg = 0; rg < 4; ++rg)
                h2L[w][q * 4 + rg][nt * 16 + r16] = f2bf(gelu_f(c2[rg] + br));
        }

        short8 a3 = *(const short8*)&h2L[w][r16][q * 8];
        float keep0 = 0.f, keep1 = 0.f;
        #pragma unroll
        for (int tt = 0; tt < 8; ++tt) {
            floatx4 c3 = __builtin_amdgcn_mfma_f32_16x16x32_bf16(a3, B3[tt], z4, 0, 0, 0);
            float mx = fmaxf(fmaxf(c3.x, c3.y), fmaxf(c3.z, c3.w));
            mx = fmaxf(mx, __shfl_xor(mx, 16));
            mx = fmaxf(mx, __shfl_xor(mx, 32));
            if (tt == q)     keep0 = mx;
            if (tt == q + 4) keep1 = mx;
        }
        feat[(size_t)n * 128 + l]      = keep0 * bg0 + bb0;
        feat[(size_t)n * 128 + l + 64] = keep1 * bg1 + bb1;
    }
}

// ---------------------------------------------------------------------------
// Residual MLP via MFMA, with optional fused gpe pre-pass (bf16 MFMA) and
// optional fused xp-projection tail. Block 256, grid 512, 64 points/block.
// ---------------------------------------------------------------------------
__global__ __launch_bounds__(256, 2) void mlp_mfma(
    float* __restrict__ feat,
    const unsigned short* __restrict__ P1, const float* __restrict__ b1,
    const unsigned short* __restrict__ P2,
    const float* __restrict__ g, const float* __restrict__ b,
    const unsigned short* __restrict__ P_gpe, const float* __restrict__ g_pos,
    const unsigned short* __restrict__ P_proj, unsigned short* __restrict__ xpb)
{
    int t = threadIdx.x, w = t >> 6, l = t & 63;
    int q = l >> 4, r16 = l & 15;
    __shared__ __align__(16) unsigned short aS[16][136];
    __shared__ __align__(16) unsigned short hS[16][264];
    __shared__ __align__(16) float fS[16][132];

    const short8* B1 = (const short8*)P1;
    const short8* B2 = (const short8*)P2;
    short8 b1f[4][4];
    #pragma unroll
    for (int nt = 0; nt < 4; ++nt)
        #pragma unroll
        for (int ch = 0; ch < 4; ++ch)
            b1f[nt][ch] = B1[((w * 4 + nt) * 4 + ch) * 64 + l];
    short8 b2f[2][8];
    #pragma unroll
    for (int nt = 0; nt < 2; ++nt)
        #pragma unroll
        for (int ch = 0; ch < 8; ++ch)
            b2f[nt][ch] = B2[((w * 2 + nt) * 8 + ch) * 64 + l];
    float bb1[4];
    #pragma unroll
    for (int nt = 0; nt < 4; ++nt) bb1[nt] = b1[w * 64 + nt * 16 + r16];
    float gg[2], bb[2];
    #pragma unroll
    for (int nt = 0; nt < 2; ++nt) {
        int c = w * 32 + nt * 16 + r16;
        gg[nt] = g[c] * BN_RSQ; bb[nt] = b[c];
    }
    floatx4 z4 = {0.f, 0.f, 0.f, 0.f};

    for (int itc = 0; itc < 4; ++itc) {
        int n0 = blockIdx.x * 64 + itc * 16;
        {
            int row = t >> 4, c8 = (t & 15) * 8;
            float4 fa = *(const float4*)&feat[(size_t)(n0 + row) * 128 + c8];
            float4 fb4 = *(const float4*)&feat[(size_t)(n0 + row) * 128 + c8 + 4];
            *(float4*)&fS[row][c8] = fa;
            *(float4*)&fS[row][c8 + 4] = fb4;
            if (!P_gpe) {
                unsigned u0 = (unsigned)f2bf(fa.x) | ((unsigned)f2bf(fa.y) << 16);
                unsigned u1 = (unsigned)f2bf(fa.z) | ((unsigned)f2bf(fa.w) << 16);
                unsigned u2 = (unsigned)f2bf(fb4.x) | ((unsigned)f2bf(fb4.y) << 16);
                unsigned u3 = (unsigned)f2bf(fb4.z) | ((unsigned)f2bf(fb4.w) << 16);
                *(uint4*)&aS[row][c8] = make_uint4(u0, u1, u2, u3);
            }
        }
        __syncthreads();

        if (P_gpe) {
            const short8* Bg = (const short8*)P_gpe;
            floatx4 cg[2] = {z4, z4};
            #pragma unroll
            for (int ch = 0; ch < 2; ++ch) {
                const float* gp = &g_pos[(size_t)(n0 + r16) * 64 + ch * 32 + q * 8];
                float4 ga = *(const float4*)gp;
                float4 gb4 = *(const float4*)(gp + 4);
                short8 ag;
                ag[0] = f2bf(ga.x); ag[1] = f2bf(ga.y); ag[2] = f2bf(ga.z); ag[3] = f2bf(ga.w);
                ag[4] = f2bf(gb4.x); ag[5] = f2bf(gb4.y); ag[6] = f2bf(gb4.z); ag[7] = f2bf(gb4.w);
                #pragma unroll
                for (int nt = 0; nt < 2; ++nt)
                    cg[nt] = __builtin_amdgcn_mfma_f32_16x16x32_bf16(ag, Bg[((2 * w + nt) * 2 + ch) * 64 + l], cg[nt], 0, 0, 0);
            }
            #pragma unroll
            for (int nt = 0; nt < 2; ++nt) {
                int c = (2 * w + nt) * 16 + r16;
                #pragma unroll
                for (int rg = 0; rg < 4; ++rg) {
                    int row = q * 4 + rg;
                    float v = fS[row][c] + cg[nt][rg];
                    fS[row][c] = v;
                    aS[row][c] = f2bf(v);
                }
            }
            __syncthreads();
        }

        floatx4 acc1[4];
        #pragma unroll
        for (int nt = 0; nt < 4; ++nt) acc1[nt] = z4;
        #pragma unroll
        for (int ch = 0; ch < 4; ++ch) {
            short8 af = *(const short8*)&aS[r16][ch * 32 + q * 8];
            #pragma unroll
            for (int nt = 0; nt < 4; ++nt)
                acc1[nt] = __builtin_amdgcn_mfma_f32_16x16x32_bf16(af, b1f[nt][ch], acc1[nt], 0, 0, 0);
        }
        #pragma unroll
        for (int nt = 0; nt < 4; ++nt) {
            int c = w * 64 + nt * 16 + r16;
            #pragma unroll
            for (int rg = 0; rg < 4; ++rg)
                hS[q * 4 + rg][c] = f2bf(gelu_f(acc1[nt][rg] + bb1[nt]));
        }
        __syncthreads();

        floatx4 acc2[2];
        #pragma unroll
        for (int nt = 0; nt < 2; ++nt) acc2[nt] = z4;
        #pragma unroll
        for (int ch = 0; ch < 8; ++ch) {
            short8 af = *(const short8*)&hS[r16][ch * 32 + q * 8];
            #pragma unroll
            for (int nt = 0; nt < 2; ++nt)
                acc2[nt] = __builtin_amdgcn_mfma_f32_16x16x32_bf16(af, b2f[nt][ch], acc2[nt], 0, 0, 0);
        }
        #pragma unroll
        for (int nt = 0; nt < 2; ++nt) {
            int c = w * 32 + nt * 16 + r16;
            #pragma unroll
            for (int rg = 0; rg < 4; ++rg) {
                int row = q * 4 + rg;
                float v = fS[row][c] + acc2[nt][rg] * gg[nt] + bb[nt];
                feat[(size_t)(n0 + row) * 128 + c] = v;
                if (P_proj) aS[row][c] = f2bf(v);
            }
        }
        if (P_proj) {
            __syncthreads();
            const short8* Bp = (const short8*)P_proj;
            #pragma unroll
            for (int nt = 0; nt < 2; ++nt) {
                int tg = w * 2 + nt;
                floatx4 ap = z4;
                #pragma unroll
                for (int ch = 0; ch < 4; ++ch) {
                    short8 af = *(const short8*)&aS[r16][ch * 32 + q * 8];
                    ap = __builtin_amdgcn_mfma_f32_16x16x32_bf16(af, Bp[(tg * 4 + ch) * 64 + l], ap, 0, 0, 0);
                }
                #pragma unroll
                for (int rg = 0; rg < 4; ++rg)
                    xpb[(size_t)(n0 + q * 4 + rg) * 128 + tg * 16 + r16] = f2bf(ap[rg]);
            }
        }
        __syncthreads();
    }
}

// ---------------------------------------------------------------------------
// xp = feat @ proj (128->128), bf16 output (depths 1,3).
// ---------------------------------------------------------------------------
__global__ __launch_bounds__(256) void linear_mfma(
    const float* __restrict__ feat, const unsigned short* __restrict__ P,
    unsigned short* __restrict__ xp)
{
    int t = threadIdx.x, w = t >> 6, l = t & 63;
    int q = l >> 4, r16 = l & 15;
    __shared__ __align__(16) unsigned short aS[16][136];
    const short8* B = (const short8*)P;
    short8 bf[2][4];
    #pragma unroll
    for (int nt = 0; nt < 2; ++nt)
        #pragma unroll
        for (int ch = 0; ch < 4; ++ch)
            bf[nt][ch] = B[((w * 2 + nt) * 4 + ch) * 64 + l];
    floatx4 z4 = {0.f, 0.f, 0.f, 0.f};

    for (int itc = 0; itc < 4; ++itc) {
        int n0 = blockIdx.x * 64 + itc * 16;
        {
            int row = t >> 4, c8 = (t & 15) * 8;
            float4 fa = *(const float4*)&feat[(size_t)(n0 + row) * 128 + c8];
            float4 fb4 = *(const float4*)&feat[(size_t)(n0 + row) * 128 + c8 + 4];
            unsigned u0 = (unsigned)f2bf(fa.x) | ((unsigned)f2bf(fa.y) << 16);
            unsigned u1 = (unsigned)f2bf(fa.z) | ((unsigned)f2bf(fa.w) << 16);
            unsigned u2 = (unsigned)f2bf(fb4.x) | ((unsigned)f2bf(fb4.y) << 16);
            unsigned u3 = (unsigned)f2bf(fb4.z) | ((unsigned)f2bf(fb4.w) << 16);
            *(uint4*)&aS[row][c8] = make_uint4(u0, u1, u2, u3);
        }
        __syncthreads();
        floatx4 acc[2];
        #pragma unroll
        for (int nt = 0; nt < 2; ++nt) acc[nt] = z4;
        #pragma unroll
        for (int ch = 0; ch < 4; ++ch) {
            short8 af = *(const short8*)&aS[r16][ch * 32 + q * 8];
            #pragma unroll
            for (int nt = 0; nt < 2; ++nt)
                acc[nt] = __builtin_amdgcn_mfma_f32_16x16x32_bf16(af, bf[nt][ch], acc[nt], 0, 0, 0);
        }
        #pragma unroll
        for (int nt = 0; nt < 2; ++nt) {
            int c = w * 32 + nt * 16 + r16;
            #pragma unroll
            for (int rg = 0; rg < 4; ++rg)
                xp[(size_t)(n0 + q * 4 + rg) * 128 + c] = f2bf(acc[nt][rg]);
        }
        __syncthreads();
    }
}

// ---------------------------------------------------------------------------
// Postproj: out = BN(feat) @ pp_w (128->256), fp32 out.
// ---------------------------------------------------------------------------
__global__ __launch_bounds__(256) void postproj_mfma(
    float* __restrict__ out, const float* __restrict__ feat,
    const float* __restrict__ g, const float* __restrict__ b,
    const unsigned short* __restrict__ P)
{
    int t = threadIdx.x, w = t >> 6, l = t & 63;
    int q = l >> 4, r16 = l & 15;
    __shared__ __align__(16) unsigned short aS[16][136];
    const short8* B = (const short8*)P;
    short8 bf[4][4];
    #pragma unroll
    for (int nt = 0; nt < 4; ++nt)
        #pragma unroll
        for (int ch = 0; ch < 4; ++ch)
            bf[nt][ch] = B[((w * 4 + nt) * 4 + ch) * 64 + l];
    floatx4 z4 = {0.f, 0.f, 0.f, 0.f};

    for (int itc = 0; itc < 4; ++itc) {
        int n0 = blockIdx.x * 64 + itc * 16;
        {
            int row = t >> 4, c8 = (t & 15) * 8;
            const float* fp = &feat[(size_t)(n0 + row) * 128 + c8];
            float4 fa = *(const float4*)fp;
            float4 fb4 = *(const float4*)(fp + 4);
            float4 ga = *(const float4*)&g[c8], gb4 = *(const float4*)&g[c8 + 4];
            float4 ba = *(const float4*)&b[c8], bb4 = *(const float4*)&b[c8 + 4];
            unsigned u0 = (unsigned)f2bf(fa.x * ga.x * BN_RSQ + ba.x) | ((unsigned)f2bf(fa.y * ga.y * BN_RSQ + ba.y) << 16);
            unsigned u1 = (unsigned)f2bf(fa.z * ga.z * BN_RSQ + ba.z) | ((unsigned)f2bf(fa.w * ga.w * BN_RSQ + ba.w) << 16);
            unsigned u2 = (unsigned)f2bf(fb4.x * gb4.x * BN_RSQ + bb4.x) | ((unsigned)f2bf(fb4.y * gb4.y * BN_RSQ + bb4.y) << 16);
            unsigned u3 = (unsigned)f2bf(fb4.z * gb4.z * BN_RSQ + bb4.z) | ((unsigned)f2bf(fb4.w * gb4.w * BN_RSQ + bb4.w) << 16);
            *(uint4*)&aS[row][c8] = make_uint4(u0, u1, u2, u3);
        }
        __syncthreads();
        floatx4 acc[4];
        #pragma unroll
        for (int nt = 0; nt < 4; ++nt) acc[nt] = z4;
        #pragma unroll
        for (int ch = 0; ch < 4; ++ch) {
            short8 af = *(const short8*)&aS[r16][ch * 32 + q * 8];
            #pragma unroll
            for (int nt = 0; nt < 4; ++nt)
                acc[nt] = __builtin_amdgcn_mfma_f32_16x16x32_bf16(af, bf[nt][ch], acc[nt], 0, 0, 0);
        }
        #pragma unroll
        for (int nt = 0; nt < 4; ++nt) {
            int c = w * 64 + nt * 16 + r16;
            #pragma unroll
            for (int rg = 0; rg < 4; ++rg)
                out[(size_t)(n0 + q * 4 + rg) * 256 + c] = acc[nt][rg];
        }
        __syncthreads();
    }
}

// ---------------------------------------------------------------------------
// LFA v4: 8 points/wave, grid 1024 (12 waves/CU). 4 independent waves, zero
// barriers. Padded tv GEMM rows discarded via q<2 guard.
// ---------------------------------------------------------------------------
__global__ __launch_bounds__(256, 2) void lfa_mfma3(
    float* __restrict__ feat, const unsigned short* __restrict__ xpb,
    const float* __restrict__ dxyz, const int* __restrict__ knn,
    const float* __restrict__ w1, const float* __restrict__ b1,
    const unsigned short* __restrict__ P_w3a, const float* __restrict__ Weff,
    const float* __restrict__ cbias, const unsigned short* __restrict__ P_w3b,
    const float* __restrict__ b3b,
    const float* __restrict__ lg, const float* __restrict__ lb)
{
    int w = threadIdx.x >> 6, l = threadIdx.x & 63;
    int q = l >> 4, r16 = l & 15;

    __shared__ __align__(16) float dxS[4][8][64];
    __shared__ __align__(16) unsigned short plA[4][16][72];
    __shared__ __align__(16) unsigned short tvS[4][8][132];
    __shared__ __align__(16) unsigned short gS[4][16][136];
    __shared__ int idS[4][128];

    int nbase = blockIdx.x * 32 + w * 8;

    #pragma unroll
    for (int i = 0; i < 2; ++i)
        idS[w][i * 64 + l] = knn[(size_t)nbase * 16 + i * 64 + l];
    #pragma unroll
    for (int i = 0; i < 6; ++i) {
        int gI = i * 64 + l;                 // 0..383
        int p = gI / 48, rr = gI % 48;
        int k = rr / 3, d = rr - k * 3;
        dxS[w][p][k * 4 + d] = dxyz[(size_t)nbase * 48 + gI];
    }

    short8 bfr[8][4];
    {
        const short8* bp = (const short8*)P_w3b;
        #pragma unroll
        for (int tt = 0; tt < 8; ++tt)
            #pragma unroll
            for (int ch = 0; ch < 4; ++ch)
                bfr[tt][ch] = bp[(tt * 4 + ch) * 64 + l];
    }
    int c0 = 2 * l;
    float2 we0 = *(const float2*)&Weff[c0];
    float2 we1 = *(const float2*)&Weff[128 + c0];
    float2 we2 = *(const float2*)&Weff[256 + c0];
    float w1r0 = w1[l], w1r1 = w1[64 + l], w1r2 = w1[128 + l], b1l = b1[l];
    float b3b0 = b3b[l], b3b1 = b3b[l + 64];
    float lg0 = lg[l] * BN_RSQ, lg1 = lg[l + 64] * BN_RSQ;
    float lb0 = lb[l], lb1 = lb[l + 64];
    floatx4 z4 = {0.f, 0.f, 0.f, 0.f};

    // p_local for 8 points (lane l owns hidden dim l)
    for (int p = 0; p < 8; ++p) {
        float m = -1e30f;
        #pragma unroll
        for (int k = 0; k < 16; ++k) {
            float4 d4 = *(const float4*)&dxS[w][p][k * 4];
            m = fmaxf(m, b1l + d4.x * w1r0 + d4.y * w1r1 + d4.z * w1r2);
        }
        plA[w][p][l] = f2bf(m);
    }

    // tv = cbias + pl @ w3a_bot : rows 8-15 of A are garbage, discarded below
    {
        floatx4 tacc[8];
        #pragma unroll
        for (int tt = 0; tt < 8; ++tt) tacc[tt] = z4;
        const short8* bpA = (const short8*)P_w3a;
        #pragma unroll
        for (int ch = 0; ch < 2; ++ch) {
            short8 af = *(const short8*)&plA[w][r16][ch * 32 + q * 8];
            #pragma unroll
            for (int tt = 0; tt < 8; ++tt)
                tacc[tt] = __builtin_amdgcn_mfma_f32_16x16x32_bf16(af, bpA[(tt * 2 + ch) * 64 + l], tacc[tt], 0, 0, 0);
        }
        if (q < 2) {
            #pragma unroll
            for (int tt = 0; tt < 8; ++tt) {
                float cb = cbias[tt * 16 + r16];
                #pragma unroll
                for (int rg = 0; rg < 4; ++rg)
                    tvS[w][q * 4 + rg][tt * 16 + r16] = f2bf(tacc[tt][rg] + cb);
            }
        }
    }

    for (int pp = 0; pp < 8; ++pp) {
        int n = nbase + pp;
        unsigned tvp = *(const unsigned*)&tvS[w][pp][c0];
        float tv0 = bf2f(tvp & 0xffffu), tv1 = bf2f(tvp >> 16);
        #pragma unroll
        for (int k = 0; k < 16; ++k) {
            float4 d4 = *(const float4*)&dxS[w][pp][k * 4];
            float s0 = tv0 + d4.x * we0.x + d4.y * we1.x + d4.z * we2.x;
            float s1 = tv1 + d4.x * we0.y + d4.y * we1.y + d4.z * we2.y;
            unsigned gw = (unsigned)f2bf(gelu_f(s0)) | ((unsigned)f2bf(gelu_f(s1)) << 16);
            *(unsigned*)&gS[w][k][c0] = gw;
        }

        floatx4 acc[8];
        #pragma unroll
        for (int tt = 0; tt < 8; ++tt) acc[tt] = z4;
        #pragma unroll
        for (int ch = 0; ch < 4; ++ch) {
            short8 af = *(const short8*)&gS[w][r16][ch * 32 + q * 8];
            #pragma unroll
            for (int tt = 0; tt < 8; ++tt)
                acc[tt] = __builtin_amdgcn_mfma_f32_16x16x32_bf16(af, bfr[tt][ch], acc[tt], 0, 0, 0);
        }

        const int* idp = &idS[w][pp * 16];
        int i0 = idp[q * 4 + 0], i1 = idp[q * 4 + 1];
        int i2 = idp[q * 4 + 2], i3 = idp[q * 4 + 3];
        float keep0 = 0.f, keep1 = 0.f;
        #pragma unroll
        for (int tt = 0; tt < 8; ++tt) {
            int cb = tt * 16 + r16;
            float v0 = acc[tt].x + bf2f(xpb[(size_t)i0 * 128 + cb]);
            float v1 = acc[tt].y + bf2f(xpb[(size_t)i1 * 128 + cb]);
            float v2 = acc[tt].z + bf2f(xpb[(size_t)i2 * 128 + cb]);
            float v3 = acc[tt].w + bf2f(xpb[(size_t)i3 * 128 + cb]);
            float mx = fmaxf(fmaxf(v0, v1), fmaxf(v2, v3));
            mx = fmaxf(mx, __shfl_xor(mx, 16));
            mx = fmaxf(mx, __shfl_xor(mx, 32));
            if (tt == q)     keep0 = mx;
            if (tt == q + 4) keep1 = mx;
        }
        size_t base = (size_t)n * 128;
        float x0 = bf2f(xpb[base + l]), x1 = bf2f(xpb[base + l + 64]);
        feat[base + l]      += (keep0 + b3b0 - x0) * lg0 + lb0;
        feat[base + l + 64] += (keep1 + b3b1 - x1) * lg1 + lb1;
    }
}

// ---------------------------------------------------------------------------
extern "C" void kernel_launch(void* const* d_in, const int* in_sizes, int n_in,
                              void* d_out, int out_size, void* d_ws, size_t ws_size,
                              hipStream_t stream) {
    const float* x       = (const float*)d_in[0];
    const float* xyz     = (const float*)d_in[1];
    const float* g_pos   = (const float*)d_in[2];
    const float* ne_w1   = (const float*)d_in[3];
    const float* ne_g1   = (const float*)d_in[4];
    const float* ne_b1   = (const float*)d_in[5];
    const float* ne_w2   = (const float*)d_in[6];
    const float* ne_g2   = (const float*)d_in[7];
    const float* ne_b2   = (const float*)d_in[8];
    const float* ne_w3   = (const float*)d_in[9];
    const float* nbr_g   = (const float*)d_in[10];
    const float* nbr_b   = (const float*)d_in[11];
    const float* gpe_w   = (const float*)d_in[12];
    const float* bm_w1   = (const float*)d_in[13];
    const float* bm_b1   = (const float*)d_in[14];
    const float* bm_w2   = (const float*)d_in[15];
    const float* bm_g    = (const float*)d_in[16];
    const float* bm_b    = (const float*)d_in[17];
    const float* lfa_proj = (const float*)d_in[18];
    const float* lfa_g   = (const float*)d_in[19];
    const float* lfa_b   = (const float*)d_in[20];
    const float* nca_w1  = (const float*)d_in[21];
    const float* nca_b1  = (const float*)d_in[22];
    const float* nca_w2  = (const float*)d_in[23];
    const float* nca_b2  = (const float*)d_in[24];
    const float* nca_w3a = (const float*)d_in[25];
    const float* nca_b3a = (const float*)d_in[26];
    const float* nca_w3b = (const float*)d_in[27];
    const float* nca_b3b = (const float*)d_in[28];
    const float* m_w1    = (const float*)d_in[29];
    const float* m_b1    = (const float*)d_in[30];
    const float* m_w2    = (const float*)d_in[31];
    const float* m_g     = (const float*)d_in[32];
    const float* m_b     = (const float*)d_in[33];
    const float* pp_g    = (const float*)d_in[34];
    const float* pp_b    = (const float*)d_in[35];
    const float* pp_w    = (const float*)d_in[36];
    const int*   knn     = (const int*)d_in[37];

    float* ws    = (float*)d_ws;
    float* dxyz  = ws;                                   // N*48
    float* feat  = dxyz + (size_t)NPTS * 48;             // N*128
    float* Weff  = feat + (size_t)NPTS * 128;            // 1536
    float* cbias = Weff + 1536;                          // 512
    unsigned short* xpb    = (unsigned short*)(cbias + 512);    // N*128
    unsigned short* P_bm1  = xpb + (size_t)NPTS * 128;   // 32768
    unsigned short* P_bm2  = P_bm1 + 32768;              // 32768
    unsigned short* P_m1   = P_bm2 + 32768;              // 65536
    unsigned short* P_m2   = P_m1 + 65536;               // 65536
    unsigned short* P_proj = P_m2 + 65536;               // 65536
    unsigned short* P_pp   = P_proj + 65536;             // 32768
    unsigned short* P_w3a  = P_pp + 32768;               // 32768
    unsigned short* P_w3b  = P_w3a + 32768;              // 65536
    unsigned short* P_ne3  = P_w3b + 65536;              // 4096
    unsigned short* P_gpe  = P_ne3 + 4096;               // 8192
    unsigned short* P_ne1  = P_gpe + 8192;               // 512
    unsigned short* P_ne2  = P_ne1 + 512;                // 1024
    float* out = (float*)d_out;

    hipLaunchKernelGGL(precompute_kernel, dim3(4), dim3(128), 0, stream,
                       nca_w1, nca_b1, nca_w2, nca_b2, nca_w3a, nca_b3a, Weff, cbias);
    hipLaunchKernelGGL(pack_all, dim3(795), dim3(64), 0, stream,
                       bm_w1, bm_w2, m_w1, m_w2, lfa_proj, pp_w, nca_w3a, nca_w3b,
                       ne_w3, gpe_w, ne_w1, ne_g1, ne_w2, ne_g2,
                       P_bm1, P_bm2, P_m1, P_m2, P_proj, P_pp, P_w3a, P_w3b,
                       P_ne3, P_gpe, P_ne1, P_ne2);
    hipLaunchKernelGGL(nbr_embed_v2, dim3(1024), dim3(256), 0, stream,
                       x, xyz, knn, ne_b1, ne_b2, P_ne1, P_ne2, P_ne3,
                       nbr_g, nbr_b, dxyz, feat);
    // bm MLP with fused gpe add and fused proj_0
    hipLaunchKernelGGL(mlp_mfma, dim3(512), dim3(256), 0, stream,
                       feat, P_bm1, bm_b1, P_bm2, bm_g, bm_b,
                       P_gpe, g_pos, P_proj, xpb);
    for (int i = 0; i < 4; ++i) {
        hipLaunchKernelGGL(lfa_mfma3, dim3(1024), dim3(256), 0, stream,
                           feat, xpb, dxyz, knn,
                           nca_w1 + (size_t)i * 192, nca_b1 + (size_t)i * 64,
                           P_w3a + (size_t)i * 8192,
                           Weff + (size_t)i * 384, cbias + (size_t)i * 128,
                           P_w3b + (size_t)i * 16384,
                           nca_b3b + (size_t)i * 128,
                           lfa_g + (size_t)i * 128, lfa_b + (size_t)i * 128);
        if (i == 0 || i == 2) {
            // xp for next depth from current feat
            hipLaunchKernelGGL(linear_mfma, dim3(512), dim3(256), 0, stream,
                               feat, P_proj + (size_t)(i + 1) * 16384, xpb);
        } else {
            int j = i >> 1;
            // interleaved MLP; for i==1 fuse proj_2
            hipLaunchKernelGGL(mlp_mfma, dim3(512), dim3(256), 0, stream,
                               feat, P_m1 + (size_t)j * 32768, m_b1 + (size_t)j * 256,
                               P_m2 + (size_t)j * 32768, m_g + (size_t)j * 128,
                               m_b + (size_t)j * 128,
                               (const unsigned short*)nullptr, (const float*)nullptr,
                               (i == 1) ? (P_proj + (size_t)2 * 16384) : (const unsigned short*)nullptr,
                               xpb);
        }
    }
    hipLaunchKernelGGL(postproj_mfma, dim3(512), dim3(256), 0, stream,
                       out, feat, pp_g, pp_b, P_pp);
}